// Round 12
// baseline (4352.983 us; speedup 1.0000x reference)
//
#include <hip/hip_runtime.h>
#include <cstdint>
#include <cstddef>

typedef unsigned short u16;
typedef __bf16 bf16x8 __attribute__((ext_vector_type(8)));
typedef float f32x4 __attribute__((ext_vector_type(4)));
typedef unsigned short u16x8 __attribute__((ext_vector_type(8)));
typedef unsigned short u16x4 __attribute__((ext_vector_type(4)));

constexpr int cV  = 50257;
constexpr int cVp = 50432;      // padded to 128/256
constexpr int cNT = cVp / 128;  // 394 head n-tiles (128-wide)
constexpr int cT  = 1024;
constexpr int cE  = 1024;
constexpr int cL  = 12;
constexpr int cFF = 4096;
constexpr int cBT = 4096;       // B*T

__device__ __forceinline__ u16 f2bf(float f) {
  union { float f; unsigned u; } x; x.f = f;
  unsigned r = x.u + 0x7fffu + ((x.u >> 16) & 1u);   // RNE
  return (u16)(r >> 16);
}

// async global->LDS, 16B per lane. dest must be linear in lane order.
__device__ __forceinline__ void gload16(const void* g, void* l) {
  __builtin_amdgcn_global_load_lds(
      (const __attribute__((address_space(1))) void*)g,
      (__attribute__((address_space(3))) void*)l, 16, 0, 0);
}

// XOR swizzle for 128B-wide LDS rows (attn): permute 16B chunks within row.
__device__ __forceinline__ int swzoff(int row, int chunk) {
  return ((chunk ^ (row & 7) ^ ((row >> 3) & 7)) << 4);
}

// bijective XCD-chunk swizzle for grids with nwg % 8 == 0 (k_gemm_s only)
__device__ __forceinline__ int xcd_swz(int id, int nwg) {
  if ((nwg & 7) == 0) { const int q = nwg >> 3; return (id & 7) * q + (id >> 3); }
  return id;
}

// ---------------- embedding ----------------
__global__ __launch_bounds__(256) void k_embed(const int* __restrict__ idx,
    const float* __restrict__ tok, const float* __restrict__ pos,
    float* __restrict__ x) {
  const int row = blockIdx.x;
  const int t = row & (cT - 1);
  const int tk = idx[row];
  const float4* tv = (const float4*)(tok + (size_t)tk * cE);
  const float4* pv = (const float4*)(pos + (size_t)t * cE);
  float4* xv = (float4*)(x + (size_t)row * cE);
  const int i = threadIdx.x;
  float4 a = tv[i];
  float4 p = pv[i];
  a.x += p.x; a.y += p.y; a.z += p.z; a.w += p.w;
  xv[i] = a;
}

// ---------------- layernorm (f32 in -> bf16 out) ----------------
__global__ __launch_bounds__(256) void k_ln(const float* __restrict__ x,
    const float* __restrict__ gw, const float* __restrict__ bw,
    u16* __restrict__ out) {
  const int row = blockIdx.x;
  const int t = threadIdx.x;
  const float4 v = ((const float4*)(x + (size_t)row * cE))[t];
  float s1 = v.x + v.y + v.z + v.w;
  float s2 = v.x * v.x + v.y * v.y + v.z * v.z + v.w * v.w;
  #pragma unroll
  for (int off = 32; off; off >>= 1) {
    s1 += __shfl_xor(s1, off);
    s2 += __shfl_xor(s2, off);
  }
  __shared__ float red[8];
  const int wid = t >> 6;
  if ((t & 63) == 0) { red[wid] = s1; red[4 + wid] = s2; }
  __syncthreads();
  s1 = red[0] + red[1] + red[2] + red[3];
  s2 = red[4] + red[5] + red[6] + red[7];
  const float mean = s1 * (1.0f / cE);
  const float var = s2 * (1.0f / cE) - mean * mean;
  const float rs = rsqrtf(var + 1e-5f);
  const float4 g4 = ((const float4*)gw)[t];
  const float4 b4 = ((const float4*)bw)[t];
  u16x4 o;
  o[0] = f2bf((v.x - mean) * rs * g4.x + b4.x);
  o[1] = f2bf((v.y - mean) * rs * g4.y + b4.y);
  o[2] = f2bf((v.z - mean) * rs * g4.z + b4.z);
  o[3] = f2bf((v.w - mean) * rs * g4.w + b4.w);
  *(u16x4*)(out + (size_t)row * cE + t * 4) = o;
}

// ------- weight convert+transpose: f32[K][N] -> bf16[N][K], vectorized -------
__global__ __launch_bounds__(256) void k_cvt_t(const float* __restrict__ src,
    u16* __restrict__ dst, int K, int Nsrc, size_t sstride, size_t dstride) {
  __shared__ float tile[32][65];
  const float* s = src + blockIdx.z * sstride;
  u16* d = dst + blockIdx.z * dstride;
  const int n0 = blockIdx.x * 64, k0 = blockIdx.y * 32;
  const int t = threadIdx.x;
  #pragma unroll
  for (int p = 0; p < 2; ++p) {
    const int li = p * 256 + t;
    const int k = li >> 4;            // 0..31
    const int n4 = (li & 15) * 4;     // 0..60
    const float* sp = s + (size_t)(k0 + k) * Nsrc + n0 + n4;
    if ((n0 + n4 + 3 < Nsrc) && ((((size_t)(k0 + k) * Nsrc + n0 + n4) & 3) == 0)) {
      const float4 f = *(const float4*)sp;
      tile[k][n4] = f.x; tile[k][n4 + 1] = f.y;
      tile[k][n4 + 2] = f.z; tile[k][n4 + 3] = f.w;
    } else {
      #pragma unroll
      for (int i = 0; i < 4; ++i)
        tile[k][n4 + i] = (n0 + n4 + i < Nsrc) ? sp[i] : 0.0f;
    }
  }
  __syncthreads();
  #pragma unroll
  for (int p = 0; p < 2; ++p) {
    const int si = p * 256 + t;
    const int n = si >> 3;            // 0..63
    const int k4 = (si & 7) * 4;      // 0..28
    u16x4 o;
    #pragma unroll
    for (int i = 0; i < 4; ++i) o[i] = f2bf(tile[k4 + i][n]);
    *(u16x4*)(d + (size_t)(n0 + n) * K + k0 + k4) = o;
  }
}

// ============== 128x128 GEMM, BK=32, m97 geometry (256 thr, 4 waves) ==============
// C[M,Nout] = A[M][K](bf16) @ Bt[Npad][K](bf16)^T. 4 waves (2x2), 64x64 per
// wave, acc 4x4. VGPR ~112, LDS 32KB (2 dbuf x 16KB) -> 4 blocks/CU. The
// 4-wave barrier domain + 4 independent blocks/CU is the m97 overlap regime
// (912 TF measured) vs 512-thr/2-block (648 TF, rounds 5-10). NO
// launch_bounds occupancy floor (round-9 spill lesson); no pinning (m141);
// plain stores (round-8 NT lesson). Rows 64B = 4 x 16B chunks XOR-swizzled
// by (row>>1)&3 (2-way = free); global source pre-swizzled.
// EPI: 0 bf16 qkv slabs | 2 bf16 gelu | 3 f32 head + fused softmax partials
template<int EPI>
__global__ __launch_bounds__(256) void k_gemm2(
    const u16* __restrict__ A, const u16* __restrict__ Bt,
    const float* __restrict__ bias, u16* __restrict__ obf,
    float* __restrict__ of, int K, int Nout, int ntile, int mt,
    float* __restrict__ pm, float* __restrict__ ps) {
  __shared__ __align__(16) char smem[32768];
  const int tid = threadIdx.x;
  const int lane = tid & 63;
  const int wid = tid >> 6;           // 0..3
  const int wg = (int)blockIdx.x;
  const int bm = wg % mt;             // bm-fast: all CUs sweep same B panel
  const int bn = wg / mt;
  const int wm = wid >> 1, wn = wid & 1;
  const int l15 = lane & 15, lg = lane >> 4;

  f32x4 acc[4][4];
  #pragma unroll
  for (int i = 0; i < 4; ++i)
    #pragma unroll
    for (int j = 0; j < 4; ++j) { f32x4 z = {0.f,0.f,0.f,0.f}; acc[i][j] = z; }

  const u16* Ab = A + (size_t)(bm * 128) * K;
  const u16* Bb = Bt + (size_t)(bn * 128) * K;
  const int nt = K >> 5;

  auto stage = [&](int t) {
    char* buf = smem + ((t & 1) ? 16384 : 0);
    const int kt = t << 5;
    #pragma unroll
    for (int p = 0; p < 2; ++p) {       // A tile: 128 rows x 32 k (8KB)
      const int L = p * 256 + tid;
      const int r = L >> 2, c = L & 3;
      gload16(Ab + (size_t)r * K + kt + ((c ^ ((r >> 1) & 3)) << 3),
              buf + L * 16);
    }
    #pragma unroll
    for (int p = 0; p < 2; ++p) {       // B tile (8KB)
      const int L = p * 256 + tid;
      const int r = L >> 2, c = L & 3;
      gload16(Bb + (size_t)r * K + kt + ((c ^ ((r >> 1) & 3)) << 3),
              buf + 8192 + L * 16);
    }
  };

  stage(0);
  for (int t = 0; t < nt; ++t) {
    __syncthreads();                     // tile t landed; readers of t-1 done
    if (t + 1 < nt) stage(t + 1);        // overlap loads with compute(t)
    char* cs = smem + ((t & 1) ? 16384 : 0);
    const char* csB = cs + 8192;
    bf16x8 af[4], bfr[4];
    #pragma unroll
    for (int mi = 0; mi < 4; ++mi) {
      const int row = wm * 64 + mi * 16 + l15;
      af[mi] = *(const bf16x8*)(cs + row * 64 + ((lg ^ ((row >> 1) & 3)) << 4));
    }
    #pragma unroll
    for (int ni = 0; ni < 4; ++ni) {
      const int row = wn * 64 + ni * 16 + l15;
      bfr[ni] = *(const bf16x8*)(csB + row * 64 + ((lg ^ ((row >> 1) & 3)) << 4));
    }
    #pragma unroll
    for (int ni = 0; ni < 4; ++ni)
      #pragma unroll
      for (int mi = 0; mi < 4; ++mi)
        acc[mi][ni] = __builtin_amdgcn_mfma_f32_16x16x32_bf16(af[mi], bfr[ni], acc[mi][ni], 0, 0, 0);
  }

  // ---- epilogue ----
  if constexpr (EPI == 3) {
    __syncthreads();                      // repurpose smem
    float* pb = (float*)smem;             // [128][2][2]
    #pragma unroll
    for (int mi = 0; mi < 4; ++mi) {
      const int grow = bm * 128 + wm * 64 + mi * 16 + lg * 4;
      float rm[4];
      #pragma unroll
      for (int r = 0; r < 4; ++r) rm[r] = -1e30f;
      #pragma unroll
      for (int ni = 0; ni < 4; ++ni) {
        const int gcol = bn * 128 + wn * 64 + ni * 16 + l15;
        const bool ok = gcol < Nout;
        const float bb = ok ? bias[gcol] : 0.0f;
        #pragma unroll
        for (int r = 0; r < 4; ++r) {
          const float v = ok ? (acc[mi][ni][r] + bb) : -1e30f;
          acc[mi][ni][r] = v;
          if (ok) of[(size_t)(grow + r) * Nout + gcol] = v;
          rm[r] = fmaxf(rm[r], v);
        }
      }
      #pragma unroll
      for (int r = 0; r < 4; ++r) {
        float m = rm[r];
        #pragma unroll
        for (int off = 1; off < 16; off <<= 1) m = fmaxf(m, __shfl_xor(m, off));
        float s = 0.f;
        #pragma unroll
        for (int ni = 0; ni < 4; ++ni) s += __expf(acc[mi][ni][r] - m);
        #pragma unroll
        for (int off = 1; off < 16; off <<= 1) s += __shfl_xor(s, off);
        if (l15 == 0) {
          const int lrow = wm * 64 + mi * 16 + lg * 4 + r;
          pb[(lrow * 2 + wn) * 2] = m;
          pb[(lrow * 2 + wn) * 2 + 1] = s;
        }
      }
    }
    __syncthreads();
    if (tid < 128) {
      float m = -1e30f, s = 0.f;
      #pragma unroll
      for (int q = 0; q < 2; ++q) {
        const float m2 = pb[(tid * 2 + q) * 2];
        const float s2 = pb[(tid * 2 + q) * 2 + 1];
        const float M = fmaxf(m, m2);
        s = s * __expf(m - M) + s2 * __expf(m2 - M);
        m = M;
      }
      const size_t grow = (size_t)(bm * 128 + tid);
      pm[grow * ntile + bn] = m;
      ps[grow * ntile + bn] = s;
    }
  } else {
    #pragma unroll
    for (int mi = 0; mi < 4; ++mi) {
      const int grow = bm * 128 + wm * 64 + mi * 16 + lg * 4;
      #pragma unroll
      for (int ni = 0; ni < 4; ++ni) {
        const int gcol = bn * 128 + wn * 64 + ni * 16 + l15;
        #pragma unroll
        for (int r = 0; r < 4; ++r) {
          const float a = acc[mi][ni][r];
          if constexpr (EPI == 0) {
            obf[(size_t)(gcol >> 10) * 4194304 + (size_t)(grow + r) * 1024 + (gcol & 1023)] = f2bf(a);
          } else {
            const float gv = a + bias[gcol];
            obf[(size_t)(grow + r) * Nout + gcol] = f2bf(0.5f * gv * (1.0f + erff(gv * 0.70710678118f)));
          }
        }
      }
    }
  }
}

// ------- small-M pipelined GEMM: 64x128 tile, BK=64, residual += -------
__global__ __launch_bounds__(256) void k_gemm_s(
    const u16* __restrict__ A, const u16* __restrict__ Bt,
    const float* __restrict__ bias, float* __restrict__ of,
    int K, int Nout, int mt) {
  __shared__ __align__(16) char smem[49152];
  const int tid = threadIdx.x;
  const int lane = tid & 63;
  const int wid = tid >> 6;
  const int wg = xcd_swz((int)blockIdx.x, (int)gridDim.x);
  const int bm = wg % mt;
  const int bn = wg / mt;
  const int wr = wid >> 1, wc = wid & 1;
  const int l15 = lane & 15, lg = lane >> 4;

  f32x4 acc[2][4];
  #pragma unroll
  for (int i = 0; i < 2; ++i)
    #pragma unroll
    for (int j = 0; j < 4; ++j) { f32x4 z = {0.f,0.f,0.f,0.f}; acc[i][j] = z; }

  const u16* Ab = A + (size_t)(bm * 64) * K;
  const u16* Bb = Bt + (size_t)(bn * 128) * K;
  const int nt = K >> 6;

  auto stage = [&](int t, char* buf) {
    const int kt = (t < nt ? t : nt - 1) << 6;
    #pragma unroll
    for (int p = 0; p < 2; ++p) {
      const int L = p * 256 + tid;
      const int row = L >> 3, cc = L & 7;
      gload16(Ab + (size_t)row * K + kt + ((cc ^ (row & 7)) << 3), buf + L * 16);
    }
    #pragma unroll
    for (int p = 0; p < 4; ++p) {
      const int L = p * 256 + tid;
      const int row = L >> 3, cc = L & 7;
      gload16(Bb + (size_t)row * K + kt + ((cc ^ (row & 7)) << 3), buf + 8192 + L * 16);
    }
  };
  stage(0, smem);
  stage(1, smem + 24576);

  for (int t = 0; t < nt; ++t) {
    char* cs = smem + ((t & 1) ? 24576 : 0);
    const char* csB = cs + 8192;
    asm volatile("s_waitcnt vmcnt(6)" ::: "memory");
    __builtin_amdgcn_s_barrier();

    bf16x8 af[2][2], bfr[4][2];
    #pragma unroll
    for (int mi = 0; mi < 2; ++mi) {
      const int row = wr * 32 + mi * 16 + l15;
      #pragma unroll
      for (int kk = 0; kk < 2; ++kk)
        af[mi][kk] = *(const bf16x8*)(cs + row * 128 + (((kk * 4 + lg) ^ (row & 7)) << 4));
    }
    #pragma unroll
    for (int ni = 0; ni < 4; ++ni) {
      const int row = wc * 64 + ni * 16 + l15;
      #pragma unroll
      for (int kk = 0; kk < 2; ++kk)
        bfr[ni][kk] = *(const bf16x8*)(csB + row * 128 + (((kk * 4 + lg) ^ (row & 7)) << 4));
    }
    __builtin_amdgcn_sched_barrier(0);
    __builtin_amdgcn_s_setprio(1);
    #pragma unroll
    for (int ni = 0; ni < 4; ++ni)
      #pragma unroll
      for (int mi = 0; mi < 2; ++mi)
        acc[mi][ni] = __builtin_amdgcn_mfma_f32_16x16x32_bf16(af[mi][0], bfr[ni][0], acc[mi][ni], 0, 0, 0);
    __builtin_amdgcn_s_setprio(0);
    __builtin_amdgcn_sched_barrier(0);
    asm volatile("s_waitcnt lgkmcnt(0)" ::: "memory");
    __builtin_amdgcn_sched_barrier(0);
    __builtin_amdgcn_s_barrier();

    stage(t + 2, cs);
    __builtin_amdgcn_sched_barrier(0);
    __builtin_amdgcn_s_setprio(1);
    #pragma unroll
    for (int ni = 0; ni < 4; ++ni)
      #pragma unroll
      for (int mi = 0; mi < 2; ++mi)
        acc[mi][ni] = __builtin_amdgcn_mfma_f32_16x16x32_bf16(af[mi][1], bfr[ni][1], acc[mi][ni], 0, 0, 0);
    __builtin_amdgcn_s_setprio(0);
    __builtin_amdgcn_sched_barrier(0);
  }
  asm volatile("s_waitcnt vmcnt(0)" ::: "memory");

  #pragma unroll
  for (int mi = 0; mi < 2; ++mi) {
    const int grow = bm * 64 + wr * 32 + mi * 16 + lg * 4;
    #pragma unroll
    for (int ni = 0; ni < 4; ++ni) {
      const int gcol = bn * 128 + wc * 64 + ni * 16 + l15;
      #pragma unroll
      for (int r = 0; r < 4; ++r)
        of[(size_t)(grow + r) * Nout + gcol] += acc[mi][ni][r] + bias[gcol];
    }
  }
}

// ---------------- legacy head GEMM (f32 B, used only if d_ws too small) ----------------
__global__ __launch_bounds__(256) void k_gemm_legacy3(
    const u16* __restrict__ A, const float* __restrict__ B0,
    const float* __restrict__ bias, float* __restrict__ of,
    int M, int N, int K) {
  __shared__ u16 Al[128 * 32];
  __shared__ u16 Bl[32 * 128];
  const int tid = threadIdx.x;
  const int lane = tid & 63;
  const int wid = tid >> 6;
  const int bn = blockIdx.x;
  const int bm = blockIdx.y;
  const int wr = wid >> 1, wc = wid & 1;
  const int l15 = lane & 15, lg = lane >> 4;
  f32x4 acc[4][4];
  #pragma unroll
  for (int i = 0; i < 4; ++i)
    #pragma unroll
    for (int j = 0; j < 4; ++j) { f32x4 z = {0.f,0.f,0.f,0.f}; acc[i][j] = z; }
  const u16* Abase = A + (size_t)(bm * 128) * K;
  const int ar0 = tid >> 2;
  const int ac0 = (tid & 3) * 8;
  const int brow = tid >> 3;
  const int bc0 = (tid & 7) * 16;
  for (int kt = 0; kt < K; kt += 32) {
    *(u16x8*)(Al + ar0 * 32 + ac0) =
        *(const u16x8*)(Abase + (size_t)ar0 * K + kt + ac0);
    *(u16x8*)(Al + (ar0 + 64) * 32 + ac0) =
        *(const u16x8*)(Abase + (size_t)(ar0 + 64) * K + kt + ac0);
    {
      const float* bsrc = B0 + (size_t)(kt + brow) * N + bn * 128 + bc0;
      alignas(16) u16 tmp[16];
      const int colbase = bn * 128 + bc0;
      #pragma unroll
      for (int q = 0; q < 16; ++q)
        tmp[q] = f2bf((colbase + q < N) ? bsrc[q] : 0.0f);
      *(u16x8*)(Bl + brow * 128 + bc0) = *(const u16x8*)tmp;
      *(u16x8*)(Bl + brow * 128 + bc0 + 8) = *(const u16x8*)(tmp + 8);
    }
    __syncthreads();
    bf16x8 af[4];
    #pragma unroll
    for (int mi = 0; mi < 4; ++mi)
      af[mi] = *(const bf16x8*)(Al + (wr * 64 + mi * 16 + l15) * 32 + lg * 8);
    #pragma unroll
    for (int ni = 0; ni < 4; ++ni) {
      u16x8 tv;
      #pragma unroll
      for (int i = 0; i < 8; ++i)
        tv[i] = Bl[(lg * 8 + i) * 128 + wc * 64 + ni * 16 + l15];
      const bf16x8 bfr = __builtin_bit_cast(bf16x8, tv);
      #pragma unroll
      for (int mi = 0; mi < 4; ++mi)
        acc[mi][ni] = __builtin_amdgcn_mfma_f32_16x16x32_bf16(af[mi], bfr, acc[mi][ni], 0, 0, 0);
    }
    __syncthreads();
  }
  #pragma unroll
  for (int mi = 0; mi < 4; ++mi) {
    const int grow = bm * 128 + wr * 64 + mi * 16 + lg * 4;
    #pragma unroll
    for (int ni = 0; ni < 4; ++ni) {
      const int gcol = bn * 128 + wc * 64 + ni * 16 + l15;
      #pragma unroll
      for (int r = 0; r < 4; ++r)
        if (gcol < N) of[(size_t)(grow + r) * N + gcol] = acc[mi][ni][r] + bias[gcol];
    }
  }
}

// -------- causal flash attention: 2 q-tiles (128 rows) per block, 8 waves --------
__global__ __launch_bounds__(512, 2) void k_attn(
    const u16* __restrict__ qg, const u16* __restrict__ kg,
    const u16* __restrict__ vg, u16* __restrict__ og) {
  __shared__ u16 Kl[64 * 64];
  __shared__ u16 Vt[64 * 64];
  __shared__ u16 Pl[8][16 * 64];
  const int tid = threadIdx.x;
  const int lane = tid & 63;
  const int w = tid >> 6;            // 0..7
  const int bx = blockIdx.x;         // 0..T/128-1
  const int bh = blockIdx.y;
  const int b = bh >> 4, h = bh & 15;
  const int l15 = lane & 15, lg = lane >> 4;
  char* KlB = (char*)Kl;
  char* VtB = (char*)Vt;
  char* PlB = (char*)(Pl[w]);

  const int qwr = bx * 128 + w * 16;
  const int diagkt = qwr >> 6;
  const size_t qrow0 = (size_t)b * cT + qwr;
  bf16x8 aq[2];
  #pragma unroll
  for (int c = 0; c < 2; ++c)
    aq[c] = *(const bf16x8*)(qg + (qrow0 + l15) * cE + h * 64 + c * 32 + lg * 8);

  f32x4 acco[4];
  #pragma unroll
  for (int j = 0; j < 4; ++j) { f32x4 z = {0.f,0.f,0.f,0.f}; acco[j] = z; }
  float mrun[4], lrun[4];
  #pragma unroll
  for (int r = 0; r < 4; ++r) { mrun[r] = -1e30f; lrun[r] = 0.f; }

  const int ktmax = 2 * bx + 1;
  for (int kt = 0; kt <= ktmax; ++kt) {
    const size_t krow0 = (size_t)b * cT + kt * 64;
    {
      const int rr = tid >> 3, c8 = (tid & 7) * 8;
      *(u16x8*)(KlB + rr * 128 + swzoff(rr, c8 >> 3)) =
          *(const u16x8*)(kg + (krow0 + rr) * cE + h * 64 + c8);
      const u16x8 vv = *(const u16x8*)(vg + (krow0 + rr) * cE + h * 64 + c8);
      #pragma unroll
      for (int i = 0; i < 8; ++i)
        *(u16*)(VtB + (c8 + i) * 128 + swzoff(c8 + i, rr >> 3) + (rr & 7) * 2) = vv[i];
    }
    __syncthreads();

    if (kt <= diagkt) {
      f32x4 s[4];
      #pragma unroll
      for (int j = 0; j < 4; ++j) { f32x4 z = {0.f,0.f,0.f,0.f}; s[j] = z; }
      #pragma unroll
      for (int c = 0; c < 2; ++c) {
        #pragma unroll
        for (int j = 0; j < 4; ++j) {
          const int n = j * 16 + l15;
          const bf16x8 kb2 = *(const bf16x8*)(KlB + n * 128 + swzoff(n, c * 4 + lg));
          s[j] = __builtin_amdgcn_mfma_f32_16x16x32_bf16(aq[c], kb2, s[j], 0, 0, 0);
        }
      }

      float sv[4][4];
      const bool diag = (kt == diagkt);
      #pragma unroll
      for (int j = 0; j < 4; ++j)
        #pragma unroll
        for (int r = 0; r < 4; ++r) {
          float xs = s[j][r] * 0.125f;
          if (diag && (kt * 64 + j * 16 + l15) > (qwr + lg * 4 + r)) xs = -1e30f;
          sv[j][r] = xs;
        }

      float corr[4];
      #pragma unroll
      for (int r = 0; r < 4; ++r) {
        float mx = fmaxf(fmaxf(sv[0][r], sv[1][r]), fmaxf(sv[2][r], sv[3][r]));
        #pragma unroll
        for (int off = 1; off < 16; off <<= 1) mx = fmaxf(mx, __shfl_xor(mx, off));
        const float mnew = fmaxf(mrun[r], mx);
        corr[r] = __expf(mrun[r] - mnew);
        float rs = 0.f;
        #pragma unroll
        for (int j = 0; j < 4; ++j) {
          const float p = __expf(sv[j][r] - mnew);
          sv[j][r] = p;
          rs += p;
        }
        #pragma unroll
        for (int off = 1; off < 16; off <<= 1) rs += __shfl_xor(rs, off);
        lrun[r] = lrun[r] * corr[r] + rs;
        mrun[r] = mnew;
      }

      #pragma unroll
      for (int j = 0; j < 4; ++j)
        #pragma unroll
        for (int r = 0; r < 4; ++r) {
          const int qr = lg * 4 + r, kc = j * 16 + l15;
          *(u16*)(PlB + qr * 128 + swzoff(qr, kc >> 3) + (kc & 7) * 2) = f2bf(sv[j][r]);
          acco[j][r] *= corr[r];
        }

      #pragma unroll
      for (int c = 0; c < 2; ++c) {
        const bf16x8 pa = *(const bf16x8*)(PlB + l15 * 128 + swzoff(l15, c * 4 + lg));
        #pragma unroll
        for (int j = 0; j < 4; ++j) {
          const int n = j * 16 + l15;
          const bf16x8 vb2 = *(const bf16x8*)(VtB + n * 128 + swzoff(n, c * 4 + lg));
          acco[j] = __builtin_amdgcn_mfma_f32_16x16x32_bf16(pa, vb2, acco[j], 0, 0, 0);
        }
      }
    }
    __syncthreads();
  }

  #pragma unroll
  for (int j = 0; j < 4; ++j)
    #pragma unroll
    for (int r = 0; r < 4; ++r)
      og[(qrow0 + lg * 4 + r) * cE + h * 64 + j * 16 + l15] = f2bf(acco[j][r] / lrun[r]);
}

// ---------------- NLL from per-tile partials ----------------
__global__ __launch_bounds__(256) void k_nll2(const float* __restrict__ pm,
    const float* __restrict__ ps, const float* __restrict__ logits,
    const int* __restrict__ tgt, float* __restrict__ nll, int NT) {
  const int row = blockIdx.x * 4 + (threadIdx.x >> 6);
  const int lane = threadIdx.x & 63;
  float m = -1e30f, s = 0.f;
  for (int i = lane; i < NT; i += 64) {
    const float m2 = pm[(size_t)row * NT + i];
    const float s2 = ps[(size_t)row * NT + i];
    const float M = fmaxf(m, m2);
    s = s * __expf(m - M) + s2 * __expf(m2 - M);
    m = M;
  }
  #pragma unroll
  for (int off = 1; off < 64; off <<= 1) {
    const float m2 = __shfl_xor(m, off);
    const float s2 = __shfl_xor(s, off);
    const float M = fmaxf(m, m2);
    s = s * __expf(m - M) + s2 * __expf(m2 - M);
    m = M;
  }
  if (lane == 0)
    nll[row] = logf(s) + m - logits[(size_t)row * cV + tgt[row]];
}

// ---------------- per-row NLL over V (fallback) ----------------
__global__ __launch_bounds__(256) void k_nll(const float* __restrict__ logits,
    const int* __restrict__ tgt, float* __restrict__ nll) {
  const int row = blockIdx.x;
  const float* lp = logits + (size_t)row * cV;
  const int t = threadIdx.x;
  __shared__ float red[8];
  const int wid = t >> 6, lane = t & 63;
  float mx = -1e30f;
  for (int i = t; i < cV; i += 256) mx = fmaxf(mx, lp[i]);
  #pragma unroll
  for (int off = 32; off; off >>= 1) mx = fmaxf(mx, __shfl_xor(mx, off));
  if (lane == 0) red[wid] = mx;
  __syncthreads();
  mx = fmaxf(fmaxf(red[0], red[1]), fmaxf(red[2], red[3]));
  float s = 0.f;
  for (int i = t; i < cV; i += 256) s += __expf(lp[i] - mx);
  #pragma unroll
  for (int off = 32; off; off >>= 1) s += __shfl_xor(s, off);
  if (lane == 0) red[4 + wid] = s;
  __syncthreads();
  if (t == 0) {
    s = red[4] + red[5] + red[6] + red[7];
    nll[row] = logf(s) + mx - lp[tgt[row]];
  }
}

__global__ __launch_bounds__(256) void k_loss(const float* __restrict__ nll,
    float* __restrict__ out) {
  const int t = threadIdx.x;
  float s = 0.f;
  for (int i = t; i < cBT; i += 256) s += nll[i];
  #pragma unroll
  for (int off = 32; off; off >>= 1) s += __shfl_xor(s, off);
  __shared__ float red[4];
  if ((t & 63) == 0) red[t >> 6] = s;
  __syncthreads();
  if (t == 0) out[0] = (red[0] + red[1] + red[2] + red[3]) * (1.0f / cBT);
}

extern "C" void kernel_launch(void* const* d_in, const int* in_sizes, int n_in,
                              void* d_out, int out_size, void* d_ws, size_t ws_size,
                              hipStream_t stream) {
  const int*   idx  = (const int*)d_in[0];
  const int*   tgt  = (const int*)d_in[1];
  const float* tok  = (const float*)d_in[2];
  const float* pos  = (const float*)d_in[3];
  const float* Wq   = (const float*)d_in[4];
  const float* Wk   = (const float*)d_in[5];
  const float* Wv   = (const float*)d_in[6];
  const float* Wo   = (const float*)d_in[7];
  const float* bo   = (const float*)d_in[8];
  const float* ln1g = (const float*)d_in[9];
  const float* ln1b = (const float*)d_in[10];
  const float* ln2g = (const float*)d_in[11];
  const float* ln2b = (const float*)d_in[12];
  const float* W1   = (const float*)d_in[13];
  const float* b1   = (const float*)d_in[14];
  const float* W2   = (const float*)d_in[15];
  const float* b2   = (const float*)d_in[16];
  const float* lnfg = (const float*)d_in[17];
  const float* lnfb = (const float*)d_in[18];
  const float* Wh   = (const float*)d_in[19];
  const float* bh   = (const float*)d_in[20];

  // --- d_out scratch plan (all dead before head GEMM overwrites d_out) ---
  char* ob = (char*)d_out;
  float* x    = (float*)ob;                          // [BT,E] f32, 16 MB
  u16* hb     = (u16*)(ob + (16u << 20));
  u16* qb     = (u16*)(ob + (24u << 20));            // q/k/v contiguous slabs
  u16* kb     = (u16*)(ob + (32u << 20));
  u16* vb     = (u16*)(ob + (40u << 20));
  u16* abuf   = (u16*)(ob + (48u << 20));
  u16* fbuf   = (u16*)(ob + (56u << 20));            // [BT,FF] bf16 -> ends 88M
  u16* W3T    = (u16*)(ob + (128u << 20));           // 12 x [3][E][E] (72MB) -> 200M
  u16* WoT    = (u16*)(ob + (200u << 20));           // 12 x [E][E]   (24MB) -> 224M
  u16* W1T    = (u16*)(ob + (224u << 20));           // 12 x [FF][E]  (96MB) -> 320M
  u16* W2T    = (u16*)(ob + (320u << 20));           // 12 x [E][FF]  (96MB) -> 416M
  // --- d_ws layout ---
  u16* hf     = (u16*)d_ws;                          // 8.39 MB
  float* nll  = (float*)((char*)d_ws + 8388608);
  u16* WheadT = (u16*)((char*)d_ws + 8404992);       // [cVp][E] bf16 (103.3 MB)
  const size_t whead_end = 8404992u + (size_t)cVp * cE * 2u;
  float* pmax = (float*)((char*)d_ws + whead_end);
  float* psum = (float*)((char*)d_ws + whead_end + (size_t)cBT * cNT * 4);
  const size_t ws_need = whead_end + 2u * (size_t)cBT * cNT * 4;
  const bool fast_head = ws_size >= ws_need;

  float* logits = (float*)d_out;
  float* loss = logits + (size_t)cBT * cV;

  const dim3 blk(256);
  const size_t e2 = (size_t)cE * cE, ef = (size_t)cE * cFF;

  // weight conversion (every call)
  k_cvt_t<<<dim3(16, 32, cL), blk, 0, stream>>>(Wq, W3T,          cE, cE, e2, 3 * e2);
  k_cvt_t<<<dim3(16, 32, cL), blk, 0, stream>>>(Wk, W3T + e2,     cE, cE, e2, 3 * e2);
  k_cvt_t<<<dim3(16, 32, cL), blk, 0, stream>>>(Wv, W3T + 2 * e2, cE, cE, e2, 3 * e2);
  k_cvt_t<<<dim3(16, 32, cL), blk, 0, stream>>>(Wo, WoT, cE, cE, e2, e2);
  k_cvt_t<<<dim3(64, 32, cL), blk, 0, stream>>>(W1, W1T, cE, cFF, ef, ef);
  k_cvt_t<<<dim3(16, 128, cL), blk, 0, stream>>>(W2, W2T, cFF, cE, ef, ef);
  if (fast_head)
    k_cvt_t<<<dim3(cVp / 64, 32, 1), blk, 0, stream>>>(Wh, WheadT, cE, cV, 0, 0);

  k_embed<<<dim3(cBT), blk, 0, stream>>>(idx, tok, pos, x);
  for (int l = 0; l < cL; ++l) {
    k_ln<<<dim3(cBT), blk, 0, stream>>>(x, ln1g + l * cE, ln1b + l * cE, hb);
    k_gemm2<0><<<dim3(32 * 24), blk, 0, stream>>>(hb, W3T + l * 3 * e2,
        nullptr, qb, nullptr, cE, 3072, 0, 32, nullptr, nullptr);
    k_attn<<<dim3(8, 64), dim3(512), 0, stream>>>(qb, kb, vb, abuf);
    k_gemm_s<<<dim3(512), blk, 0, stream>>>(abuf, WoT + l * e2, bo + l * cE, x, cE, cE, 64);
    k_ln<<<dim3(cBT), blk, 0, stream>>>(x, ln2g + l * cE, ln2b + l * cE, hb);
    k_gemm2<2><<<dim3(32 * 32), blk, 0, stream>>>(hb, W1T + l * ef,
        b1 + l * cFF, fbuf, nullptr, cE, cFF, 0, 32, nullptr, nullptr);
    k_gemm_s<<<dim3(512), blk, 0, stream>>>(fbuf, W2T + l * ef, b2 + l * cE, x, cFF, cE, 64);
  }
  k_ln<<<dim3(cBT), blk, 0, stream>>>(x, lnfg, lnfb, hf);
  if (fast_head) {
    k_gemm2<3><<<dim3(32 * cNT), blk, 0, stream>>>(hf, WheadT, bh,
        nullptr, logits, cE, cV, cNT, 32, pmax, psum);
    k_nll2<<<dim3(cBT / 4), blk, 0, stream>>>(pmax, psum, logits, tgt, nll, cNT);
  } else {
    k_gemm_legacy3<<<dim3(393, 32), blk, 0, stream>>>(hf, Wh, bh, logits, cBT, cV, cE);
    k_nll<<<dim3(cBT), blk, 0, stream>>>(logits, tgt, nll);
  }
  k_loss<<<dim3(1), blk, 0, stream>>>(nll, loss);
}

// Round 13
// 4119.918 us; speedup vs baseline: 1.0566x; 1.0566x over previous
//
#include <hip/hip_runtime.h>
#include <cstdint>
#include <cstddef>

typedef unsigned short u16;
typedef __bf16 bf16x8 __attribute__((ext_vector_type(8)));
typedef float f32x4 __attribute__((ext_vector_type(4)));
typedef unsigned short u16x8 __attribute__((ext_vector_type(8)));
typedef unsigned short u16x4 __attribute__((ext_vector_type(4)));

constexpr int cV  = 50257;
constexpr int cVp = 50432;      // padded to 256
constexpr int cNT = cVp / 256;  // 197 head n-tiles
constexpr int cT  = 1024;
constexpr int cE  = 1024;
constexpr int cL  = 12;
constexpr int cFF = 4096;
constexpr int cBT = 4096;       // B*T

__device__ __forceinline__ u16 f2bf(float f) {
  union { float f; unsigned u; } x; x.f = f;
  unsigned r = x.u + 0x7fffu + ((x.u >> 16) & 1u);   // RNE
  return (u16)(r >> 16);
}

// async global->LDS, 16B per lane. dest must be linear in lane order.
__device__ __forceinline__ void gload16(const void* g, void* l) {
  __builtin_amdgcn_global_load_lds(
      (const __attribute__((address_space(1))) void*)g,
      (__attribute__((address_space(3))) void*)l, 16, 0, 0);
}

// XOR swizzle for 128B-wide LDS rows (attn): permute 16B chunks within row.
__device__ __forceinline__ int swzoff(int row, int chunk) {
  return ((chunk ^ (row & 7) ^ ((row >> 3) & 7)) << 4);
}

// bijective XCD-chunk swizzle for grids with nwg % 8 == 0 (k_gemm_s only)
__device__ __forceinline__ int xcd_swz(int id, int nwg) {
  if ((nwg & 7) == 0) { const int q = nwg >> 3; return (id & 7) * q + (id >> 3); }
  return id;
}

// ---------------- embedding ----------------
__global__ __launch_bounds__(256) void k_embed(const int* __restrict__ idx,
    const float* __restrict__ tok, const float* __restrict__ pos,
    float* __restrict__ x) {
  const int row = blockIdx.x;
  const int t = row & (cT - 1);
  const int tk = idx[row];
  const float4* tv = (const float4*)(tok + (size_t)tk * cE);
  const float4* pv = (const float4*)(pos + (size_t)t * cE);
  float4* xv = (float4*)(x + (size_t)row * cE);
  const int i = threadIdx.x;
  float4 a = tv[i];
  float4 p = pv[i];
  a.x += p.x; a.y += p.y; a.z += p.z; a.w += p.w;
  xv[i] = a;
}

// ---------------- layernorm (f32 in -> bf16 out) ----------------
__global__ __launch_bounds__(256) void k_ln(const float* __restrict__ x,
    const float* __restrict__ gw, const float* __restrict__ bw,
    u16* __restrict__ out) {
  const int row = blockIdx.x;
  const int t = threadIdx.x;
  const float4 v = ((const float4*)(x + (size_t)row * cE))[t];
  float s1 = v.x + v.y + v.z + v.w;
  float s2 = v.x * v.x + v.y * v.y + v.z * v.z + v.w * v.w;
  #pragma unroll
  for (int off = 32; off; off >>= 1) {
    s1 += __shfl_xor(s1, off);
    s2 += __shfl_xor(s2, off);
  }
  __shared__ float red[8];
  const int wid = t >> 6;
  if ((t & 63) == 0) { red[wid] = s1; red[4 + wid] = s2; }
  __syncthreads();
  s1 = red[0] + red[1] + red[2] + red[3];
  s2 = red[4] + red[5] + red[6] + red[7];
  const float mean = s1 * (1.0f / cE);
  const float var = s2 * (1.0f / cE) - mean * mean;
  const float rs = rsqrtf(var + 1e-5f);
  const float4 g4 = ((const float4*)gw)[t];
  const float4 b4 = ((const float4*)bw)[t];
  u16x4 o;
  o[0] = f2bf((v.x - mean) * rs * g4.x + b4.x);
  o[1] = f2bf((v.y - mean) * rs * g4.y + b4.y);
  o[2] = f2bf((v.z - mean) * rs * g4.z + b4.z);
  o[3] = f2bf((v.w - mean) * rs * g4.w + b4.w);
  *(u16x4*)(out + (size_t)row * cE + t * 4) = o;
}

// ------- weight convert+transpose: f32[K][N] -> bf16[N][K], vectorized -------
__global__ __launch_bounds__(256) void k_cvt_t(const float* __restrict__ src,
    u16* __restrict__ dst, int K, int Nsrc, size_t sstride, size_t dstride) {
  __shared__ float tile[32][65];
  const float* s = src + blockIdx.z * sstride;
  u16* d = dst + blockIdx.z * dstride;
  const int n0 = blockIdx.x * 64, k0 = blockIdx.y * 32;
  const int t = threadIdx.x;
  #pragma unroll
  for (int p = 0; p < 2; ++p) {
    const int li = p * 256 + t;
    const int k = li >> 4;            // 0..31
    const int n4 = (li & 15) * 4;     // 0..60
    const float* sp = s + (size_t)(k0 + k) * Nsrc + n0 + n4;
    if ((n0 + n4 + 3 < Nsrc) && ((((size_t)(k0 + k) * Nsrc + n0 + n4) & 3) == 0)) {
      const float4 f = *(const float4*)sp;
      tile[k][n4] = f.x; tile[k][n4 + 1] = f.y;
      tile[k][n4 + 2] = f.z; tile[k][n4 + 3] = f.w;
    } else {
      #pragma unroll
      for (int i = 0; i < 4; ++i)
        tile[k][n4 + i] = (n0 + n4 + i < Nsrc) ? sp[i] : 0.0f;
    }
  }
  __syncthreads();
  #pragma unroll
  for (int p = 0; p < 2; ++p) {
    const int si = p * 256 + t;
    const int n = si >> 3;            // 0..63
    const int k4 = (si & 7) * 4;      // 0..28
    u16x4 o;
    #pragma unroll
    for (int i = 0; i < 4; ++i) o[i] = f2bf(tile[k4 + i][n]);
    *(u16x4*)(d + (size_t)(n0 + n) * K + k0 + k4) = o;
  }
}

// ========= 128x256 GEMM, BK=32, 2 blocks/CU, 3-deep ring prefetch =========
// Round-11 structure (best: 651us head) + ring-3 LDS (3 x 24KB = 72KB) with
// counted vmcnt: per iter { vmcnt(3) [tile t's own loads; t+1 in flight] |
// raw s_barrier [all waves' t-loads landed + compute(t-1) done] |
// stage(t+2) into slot freed 2 iters ago | compute(t) }. Loads get ~2 full
// compute phases of latency cover; queue never drains in-loop. Last iter
// peeled with vmcnt(0). A/B vs round-11 isolates load-latency as limiter.
// (512,4): no spill (round-9 lesson). Plain stores (round-8 NT lesson).
template<int EPI>
__global__ __launch_bounds__(512, 4) void k_gemm2(
    const u16* __restrict__ A, const u16* __restrict__ Bt,
    const float* __restrict__ bias, u16* __restrict__ obf,
    float* __restrict__ of, int K, int Nout, int ntile, int mt,
    float* __restrict__ pm, float* __restrict__ ps) {
  __shared__ __align__(16) char smem[73728];      // 3 x 24KB ring
  const int tid = threadIdx.x;
  const int lane = tid & 63;
  const int wid = tid >> 6;
  const int wg = (int)blockIdx.x;
  const int bm = wg % mt;            // bm-fast: all CUs sweep same B panel
  const int bn = wg / mt;
  const int wm = wid >> 2, wn = wid & 3;
  const int l15 = lane & 15, lg = lane >> 4;

  f32x4 acc[4][4];
  #pragma unroll
  for (int i = 0; i < 4; ++i)
    #pragma unroll
    for (int j = 0; j < 4; ++j) { f32x4 z = {0.f,0.f,0.f,0.f}; acc[i][j] = z; }

  const u16* Ab = A + (size_t)(bm * 128) * K;
  const u16* Bb = Bt + (size_t)(bn * 256) * K;
  const int nt = K >> 5;

  auto stage = [&](int t) {
    char* buf = smem + (t % 3) * 24576;
    const int kt = t << 5;
    {
      const int r = tid >> 2, c = tid & 3;
      gload16(Ab + (size_t)r * K + kt + ((c ^ ((r >> 1) & 3)) << 3),
              buf + tid * 16);
    }
    #pragma unroll
    for (int p = 0; p < 2; ++p) {
      const int L = p * 512 + tid;
      const int r = L >> 2, c = L & 3;
      gload16(Bb + (size_t)r * K + kt + ((c ^ ((r >> 1) & 3)) << 3),
              buf + 8192 + L * 16);
    }
  };

  auto compute = [&](int t) {
    const char* cs = smem + (t % 3) * 24576;
    const char* csB = cs + 8192;
    bf16x8 af[4], bfr[4];
    #pragma unroll
    for (int mi = 0; mi < 4; ++mi) {
      const int row = wm * 64 + mi * 16 + l15;
      af[mi] = *(const bf16x8*)(cs + row * 64 + ((lg ^ ((row >> 1) & 3)) << 4));
    }
    #pragma unroll
    for (int ni = 0; ni < 4; ++ni) {
      const int row = wn * 64 + ni * 16 + l15;
      bfr[ni] = *(const bf16x8*)(csB + row * 64 + ((lg ^ ((row >> 1) & 3)) << 4));
    }
    #pragma unroll
    for (int ni = 0; ni < 4; ++ni)
      #pragma unroll
      for (int mi = 0; mi < 4; ++mi)
        acc[mi][ni] = __builtin_amdgcn_mfma_f32_16x16x32_bf16(af[mi], bfr[ni], acc[mi][ni], 0, 0, 0);
  };

  stage(0);
  stage(1);
  for (int t = 0; t < nt - 1; ++t) {
    asm volatile("s_waitcnt vmcnt(3)" ::: "memory");   // tile t landed (own)
    __builtin_amdgcn_sched_barrier(0);
    __builtin_amdgcn_s_barrier();                      // all waves: t landed,
    if (t + 2 < nt) stage(t + 2);                      // compute(t-1) done
    compute(t);
  }
  asm volatile("s_waitcnt vmcnt(0)" ::: "memory");     // peeled last iter
  __builtin_amdgcn_sched_barrier(0);
  __builtin_amdgcn_s_barrier();
  compute(nt - 1);

  // ---- epilogue ----
  if constexpr (EPI == 3) {
    __syncthreads();                      // repurpose smem
    float* pb = (float*)smem;             // [128][4][2]
    #pragma unroll
    for (int mi = 0; mi < 4; ++mi) {
      const int grow = bm * 128 + wm * 64 + mi * 16 + lg * 4;
      float rm[4];
      #pragma unroll
      for (int r = 0; r < 4; ++r) rm[r] = -1e30f;
      #pragma unroll
      for (int ni = 0; ni < 4; ++ni) {
        const int gcol = bn * 256 + wn * 64 + ni * 16 + l15;
        const bool ok = gcol < Nout;
        const float bb = ok ? bias[gcol] : 0.0f;
        #pragma unroll
        for (int r = 0; r < 4; ++r) {
          const float v = ok ? (acc[mi][ni][r] + bb) : -1e30f;
          acc[mi][ni][r] = v;
          if (ok) of[(size_t)(grow + r) * Nout + gcol] = v;
          rm[r] = fmaxf(rm[r], v);
        }
      }
      #pragma unroll
      for (int r = 0; r < 4; ++r) {
        float m = rm[r];
        #pragma unroll
        for (int off = 1; off < 16; off <<= 1) m = fmaxf(m, __shfl_xor(m, off));
        float s = 0.f;
        #pragma unroll
        for (int ni = 0; ni < 4; ++ni) s += __expf(acc[mi][ni][r] - m);
        #pragma unroll
        for (int off = 1; off < 16; off <<= 1) s += __shfl_xor(s, off);
        if (l15 == 0) {
          const int lrow = wm * 64 + mi * 16 + lg * 4 + r;
          pb[(lrow * 4 + wn) * 2] = m;
          pb[(lrow * 4 + wn) * 2 + 1] = s;
        }
      }
    }
    __syncthreads();
    if (tid < 128) {
      float m = -1e30f, s = 0.f;
      #pragma unroll
      for (int q = 0; q < 4; ++q) {
        const float m2 = pb[(tid * 4 + q) * 2];
        const float s2 = pb[(tid * 4 + q) * 2 + 1];
        const float M = fmaxf(m, m2);
        s = s * __expf(m - M) + s2 * __expf(m2 - M);
        m = M;
      }
      const size_t grow = (size_t)(bm * 128 + tid);
      pm[grow * ntile + bn] = m;
      ps[grow * ntile + bn] = s;
    }
  } else {
    #pragma unroll
    for (int mi = 0; mi < 4; ++mi) {
      const int grow = bm * 128 + wm * 64 + mi * 16 + lg * 4;
      #pragma unroll
      for (int ni = 0; ni < 4; ++ni) {
        const int gcol = bn * 256 + wn * 64 + ni * 16 + l15;
        #pragma unroll
        for (int r = 0; r < 4; ++r) {
          const float a = acc[mi][ni][r];
          if constexpr (EPI == 0) {
            obf[(size_t)(gcol >> 10) * 4194304 + (size_t)(grow + r) * 1024 + (gcol & 1023)] = f2bf(a);
          } else {
            const float gv = a + bias[gcol];
            obf[(size_t)(grow + r) * Nout + gcol] = f2bf(0.5f * gv * (1.0f + erff(gv * 0.70710678118f)));
          }
        }
      }
    }
  }
}

// ------- small-M pipelined GEMM: 64x128 tile, BK=64, residual += -------
__global__ __launch_bounds__(256) void k_gemm_s(
    const u16* __restrict__ A, const u16* __restrict__ Bt,
    const float* __restrict__ bias, float* __restrict__ of,
    int K, int Nout, int mt) {
  __shared__ __align__(16) char smem[49152];
  const int tid = threadIdx.x;
  const int lane = tid & 63;
  const int wid = tid >> 6;
  const int wg = xcd_swz((int)blockIdx.x, (int)gridDim.x);
  const int bm = wg % mt;
  const int bn = wg / mt;
  const int wr = wid >> 1, wc = wid & 1;
  const int l15 = lane & 15, lg = lane >> 4;

  f32x4 acc[2][4];
  #pragma unroll
  for (int i = 0; i < 2; ++i)
    #pragma unroll
    for (int j = 0; j < 4; ++j) { f32x4 z = {0.f,0.f,0.f,0.f}; acc[i][j] = z; }

  const u16* Ab = A + (size_t)(bm * 64) * K;
  const u16* Bb = Bt + (size_t)(bn * 128) * K;
  const int nt = K >> 6;

  auto stage = [&](int t, char* buf) {
    const int kt = (t < nt ? t : nt - 1) << 6;
    #pragma unroll
    for (int p = 0; p < 2; ++p) {
      const int L = p * 256 + tid;
      const int row = L >> 3, cc = L & 7;
      gload16(Ab + (size_t)row * K + kt + ((cc ^ (row & 7)) << 3), buf + L * 16);
    }
    #pragma unroll
    for (int p = 0; p < 4; ++p) {
      const int L = p * 256 + tid;
      const int row = L >> 3, cc = L & 7;
      gload16(Bb + (size_t)row * K + kt + ((cc ^ (row & 7)) << 3), buf + 8192 + L * 16);
    }
  };
  stage(0, smem);
  stage(1, smem + 24576);

  for (int t = 0; t < nt; ++t) {
    char* cs = smem + ((t & 1) ? 24576 : 0);
    const char* csB = cs + 8192;
    asm volatile("s_waitcnt vmcnt(6)" ::: "memory");
    __builtin_amdgcn_s_barrier();

    bf16x8 af[2][2], bfr[4][2];
    #pragma unroll
    for (int mi = 0; mi < 2; ++mi) {
      const int row = wr * 32 + mi * 16 + l15;
      #pragma unroll
      for (int kk = 0; kk < 2; ++kk)
        af[mi][kk] = *(const bf16x8*)(cs + row * 128 + (((kk * 4 + lg) ^ (row & 7)) << 4));
    }
    #pragma unroll
    for (int ni = 0; ni < 4; ++ni) {
      const int row = wc * 64 + ni * 16 + l15;
      #pragma unroll
      for (int kk = 0; kk < 2; ++kk)
        bfr[ni][kk] = *(const bf16x8*)(csB + row * 128 + (((kk * 4 + lg) ^ (row & 7)) << 4));
    }
    __builtin_amdgcn_sched_barrier(0);
    __builtin_amdgcn_s_setprio(1);
    #pragma unroll
    for (int ni = 0; ni < 4; ++ni)
      #pragma unroll
      for (int mi = 0; mi < 2; ++mi)
        acc[mi][ni] = __builtin_amdgcn_mfma_f32_16x16x32_bf16(af[mi][0], bfr[ni][0], acc[mi][ni], 0, 0, 0);
    __builtin_amdgcn_s_setprio(0);
    __builtin_amdgcn_sched_barrier(0);
    asm volatile("s_waitcnt lgkmcnt(0)" ::: "memory");
    __builtin_amdgcn_sched_barrier(0);
    __builtin_amdgcn_s_barrier();

    stage(t + 2, cs);
    __builtin_amdgcn_sched_barrier(0);
    __builtin_amdgcn_s_setprio(1);
    #pragma unroll
    for (int ni = 0; ni < 4; ++ni)
      #pragma unroll
      for (int mi = 0; mi < 2; ++mi)
        acc[mi][ni] = __builtin_amdgcn_mfma_f32_16x16x32_bf16(af[mi][1], bfr[ni][1], acc[mi][ni], 0, 0, 0);
    __builtin_amdgcn_s_setprio(0);
    __builtin_amdgcn_sched_barrier(0);
  }
  asm volatile("s_waitcnt vmcnt(0)" ::: "memory");

  #pragma unroll
  for (int mi = 0; mi < 2; ++mi) {
    const int grow = bm * 64 + wr * 32 + mi * 16 + lg * 4;
    #pragma unroll
    for (int ni = 0; ni < 4; ++ni) {
      const int gcol = bn * 128 + wc * 64 + ni * 16 + l15;
      #pragma unroll
      for (int r = 0; r < 4; ++r)
        of[(size_t)(grow + r) * Nout + gcol] += acc[mi][ni][r] + bias[gcol];
    }
  }
}

// ---------------- legacy head GEMM (f32 B, used only if d_ws too small) ----------------
__global__ __launch_bounds__(256) void k_gemm_legacy3(
    const u16* __restrict__ A, const float* __restrict__ B0,
    const float* __restrict__ bias, float* __restrict__ of,
    int M, int N, int K) {
  __shared__ u16 Al[128 * 32];
  __shared__ u16 Bl[32 * 128];
  const int tid = threadIdx.x;
  const int lane = tid & 63;
  const int wid = tid >> 6;
  const int bn = blockIdx.x;
  const int bm = blockIdx.y;
  const int wr = wid >> 1, wc = wid & 1;
  const int l15 = lane & 15, lg = lane >> 4;
  f32x4 acc[4][4];
  #pragma unroll
  for (int i = 0; i < 4; ++i)
    #pragma unroll
    for (int j = 0; j < 4; ++j) { f32x4 z = {0.f,0.f,0.f,0.f}; acc[i][j] = z; }
  const u16* Abase = A + (size_t)(bm * 128) * K;
  const int ar0 = tid >> 2;
  const int ac0 = (tid & 3) * 8;
  const int brow = tid >> 3;
  const int bc0 = (tid & 7) * 16;
  for (int kt = 0; kt < K; kt += 32) {
    *(u16x8*)(Al + ar0 * 32 + ac0) =
        *(const u16x8*)(Abase + (size_t)ar0 * K + kt + ac0);
    *(u16x8*)(Al + (ar0 + 64) * 32 + ac0) =
        *(const u16x8*)(Abase + (size_t)(ar0 + 64) * K + kt + ac0);
    {
      const float* bsrc = B0 + (size_t)(kt + brow) * N + bn * 128 + bc0;
      alignas(16) u16 tmp[16];
      const int colbase = bn * 128 + bc0;
      #pragma unroll
      for (int q = 0; q < 16; ++q)
        tmp[q] = f2bf((colbase + q < N) ? bsrc[q] : 0.0f);
      *(u16x8*)(Bl + brow * 128 + bc0) = *(const u16x8*)tmp;
      *(u16x8*)(Bl + brow * 128 + bc0 + 8) = *(const u16x8*)(tmp + 8);
    }
    __syncthreads();
    bf16x8 af[4];
    #pragma unroll
    for (int mi = 0; mi < 4; ++mi)
      af[mi] = *(const bf16x8*)(Al + (wr * 64 + mi * 16 + l15) * 32 + lg * 8);
    #pragma unroll
    for (int ni = 0; ni < 4; ++ni) {
      u16x8 tv;
      #pragma unroll
      for (int i = 0; i < 8; ++i)
        tv[i] = Bl[(lg * 8 + i) * 128 + wc * 64 + ni * 16 + l15];
      const bf16x8 bfr = __builtin_bit_cast(bf16x8, tv);
      #pragma unroll
      for (int mi = 0; mi < 4; ++mi)
        acc[mi][ni] = __builtin_amdgcn_mfma_f32_16x16x32_bf16(af[mi], bfr, acc[mi][ni], 0, 0, 0);
    }
    __syncthreads();
  }
  #pragma unroll
  for (int mi = 0; mi < 4; ++mi) {
    const int grow = bm * 128 + wr * 64 + mi * 16 + lg * 4;
    #pragma unroll
    for (int ni = 0; ni < 4; ++ni) {
      const int gcol = bn * 128 + wc * 64 + ni * 16 + l15;
      #pragma unroll
      for (int r = 0; r < 4; ++r)
        if (gcol < N) of[(size_t)(grow + r) * N + gcol] = acc[mi][ni][r] + bias[gcol];
    }
  }
}

// -------- causal flash attention: 2 q-tiles (128 rows) per block, 8 waves --------
__global__ __launch_bounds__(512, 2) void k_attn(
    const u16* __restrict__ qg, const u16* __restrict__ kg,
    const u16* __restrict__ vg, u16* __restrict__ og) {
  __shared__ u16 Kl[64 * 64];
  __shared__ u16 Vt[64 * 64];
  __shared__ u16 Pl[8][16 * 64];
  const int tid = threadIdx.x;
  const int lane = tid & 63;
  const int w = tid >> 6;            // 0..7
  const int bx = blockIdx.x;         // 0..T/128-1
  const int bh = blockIdx.y;
  const int b = bh >> 4, h = bh & 15;
  const int l15 = lane & 15, lg = lane >> 4;
  char* KlB = (char*)Kl;
  char* VtB = (char*)Vt;
  char* PlB = (char*)(Pl[w]);

  const int qwr = bx * 128 + w * 16;
  const int diagkt = qwr >> 6;
  const size_t qrow0 = (size_t)b * cT + qwr;
  bf16x8 aq[2];
  #pragma unroll
  for (int c = 0; c < 2; ++c)
    aq[c] = *(const bf16x8*)(qg + (qrow0 + l15) * cE + h * 64 + c * 32 + lg * 8);

  f32x4 acco[4];
  #pragma unroll
  for (int j = 0; j < 4; ++j) { f32x4 z = {0.f,0.f,0.f,0.f}; acco[j] = z; }
  float mrun[4], lrun[4];
  #pragma unroll
  for (int r = 0; r < 4; ++r) { mrun[r] = -1e30f; lrun[r] = 0.f; }

  const int ktmax = 2 * bx + 1;
  for (int kt = 0; kt <= ktmax; ++kt) {
    const size_t krow0 = (size_t)b * cT + kt * 64;
    {
      const int rr = tid >> 3, c8 = (tid & 7) * 8;
      *(u16x8*)(KlB + rr * 128 + swzoff(rr, c8 >> 3)) =
          *(const u16x8*)(kg + (krow0 + rr) * cE + h * 64 + c8);
      const u16x8 vv = *(const u16x8*)(vg + (krow0 + rr) * cE + h * 64 + c8);
      #pragma unroll
      for (int i = 0; i < 8; ++i)
        *(u16*)(VtB + (c8 + i) * 128 + swzoff(c8 + i, rr >> 3) + (rr & 7) * 2) = vv[i];
    }
    __syncthreads();

    if (kt <= diagkt) {
      f32x4 s[4];
      #pragma unroll
      for (int j = 0; j < 4; ++j) { f32x4 z = {0.f,0.f,0.f,0.f}; s[j] = z; }
      #pragma unroll
      for (int c = 0; c < 2; ++c) {
        #pragma unroll
        for (int j = 0; j < 4; ++j) {
          const int n = j * 16 + l15;
          const bf16x8 kb2 = *(const bf16x8*)(KlB + n * 128 + swzoff(n, c * 4 + lg));
          s[j] = __builtin_amdgcn_mfma_f32_16x16x32_bf16(aq[c], kb2, s[j], 0, 0, 0);
        }
      }

      float sv[4][4];
      const bool diag = (kt == diagkt);
      #pragma unroll
      for (int j = 0; j < 4; ++j)
        #pragma unroll
        for (int r = 0; r < 4; ++r) {
          float xs = s[j][r] * 0.125f;
          if (diag && (kt * 64 + j * 16 + l15) > (qwr + lg * 4 + r)) xs = -1e30f;
          sv[j][r] = xs;
        }

      float corr[4];
      #pragma unroll
      for (int r = 0; r < 4; ++r) {
        float mx = fmaxf(fmaxf(sv[0][r], sv[1][r]), fmaxf(sv[2][r], sv[3][r]));
        #pragma unroll
        for (int off = 1; off < 16; off <<= 1) mx = fmaxf(mx, __shfl_xor(mx, off));
        const float mnew = fmaxf(mrun[r], mx);
        corr[r] = __expf(mrun[r] - mnew);
        float rs = 0.f;
        #pragma unroll
        for (int j = 0; j < 4; ++j) {
          const float p = __expf(sv[j][r] - mnew);
          sv[j][r] = p;
          rs += p;
        }
        #pragma unroll
        for (int off = 1; off < 16; off <<= 1) rs += __shfl_xor(rs, off);
        lrun[r] = lrun[r] * corr[r] + rs;
        mrun[r] = mnew;
      }

      #pragma unroll
      for (int j = 0; j < 4; ++j)
        #pragma unroll
        for (int r = 0; r < 4; ++r) {
          const int qr = lg * 4 + r, kc = j * 16 + l15;
          *(u16*)(PlB + qr * 128 + swzoff(qr, kc >> 3) + (kc & 7) * 2) = f2bf(sv[j][r]);
          acco[j][r] *= corr[r];
        }

      #pragma unroll
      for (int c = 0; c < 2; ++c) {
        const bf16x8 pa = *(const bf16x8*)(PlB + l15 * 128 + swzoff(l15, c * 4 + lg));
        #pragma unroll
        for (int j = 0; j < 4; ++j) {
          const int n = j * 16 + l15;
          const bf16x8 vb2 = *(const bf16x8*)(VtB + n * 128 + swzoff(n, c * 4 + lg));
          acco[j] = __builtin_amdgcn_mfma_f32_16x16x32_bf16(pa, vb2, acco[j], 0, 0, 0);
        }
      }
    }
    __syncthreads();
  }

  #pragma unroll
  for (int j = 0; j < 4; ++j)
    #pragma unroll
    for (int r = 0; r < 4; ++r)
      og[(qrow0 + lg * 4 + r) * cE + h * 64 + j * 16 + l15] = f2bf(acco[j][r] / lrun[r]);
}

// ---------------- NLL from per-tile partials ----------------
__global__ __launch_bounds__(256) void k_nll2(const float* __restrict__ pm,
    const float* __restrict__ ps, const float* __restrict__ logits,
    const int* __restrict__ tgt, float* __restrict__ nll, int NT) {
  const int row = blockIdx.x * 4 + (threadIdx.x >> 6);
  const int lane = threadIdx.x & 63;
  float m = -1e30f, s = 0.f;
  for (int i = lane; i < NT; i += 64) {
    const float m2 = pm[(size_t)row * NT + i];
    const float s2 = ps[(size_t)row * NT + i];
    const float M = fmaxf(m, m2);
    s = s * __expf(m - M) + s2 * __expf(m2 - M);
    m = M;
  }
  #pragma unroll
  for (int off = 1; off < 64; off <<= 1) {
    const float m2 = __shfl_xor(m, off);
    const float s2 = __shfl_xor(s, off);
    const float M = fmaxf(m, m2);
    s = s * __expf(m - M) + s2 * __expf(m2 - M);
    m = M;
  }
  if (lane == 0)
    nll[row] = logf(s) + m - logits[(size_t)row * cV + tgt[row]];
}

// ---------------- per-row NLL over V (fallback) ----------------
__global__ __launch_bounds__(256) void k_nll(const float* __restrict__ logits,
    const int* __restrict__ tgt, float* __restrict__ nll) {
  const int row = blockIdx.x;
  const float* lp = logits + (size_t)row * cV;
  const int t = threadIdx.x;
  __shared__ float red[8];
  const int wid = t >> 6, lane = t & 63;
  float mx = -1e30f;
  for (int i = t; i < cV; i += 256) mx = fmaxf(mx, lp[i]);
  #pragma unroll
  for (int off = 32; off; off >>= 1) mx = fmaxf(mx, __shfl_xor(mx, off));
  if (lane == 0) red[wid] = mx;
  __syncthreads();
  mx = fmaxf(fmaxf(red[0], red[1]), fmaxf(red[2], red[3]));
  float s = 0.f;
  for (int i = t; i < cV; i += 256) s += __expf(lp[i] - mx);
  #pragma unroll
  for (int off = 32; off; off >>= 1) s += __shfl_xor(s, off);
  if (lane == 0) red[4 + wid] = s;
  __syncthreads();
  if (t == 0) {
    s = red[4] + red[5] + red[6] + red[7];
    nll[row] = logf(s) + mx - lp[tgt[row]];
  }
}

__global__ __launch_bounds__(256) void k_loss(const float* __restrict__ nll,
    float* __restrict__ out) {
  const int t = threadIdx.x;
  float s = 0.f;
  for (int i = t; i < cBT; i += 256) s += nll[i];
  #pragma unroll
  for (int off = 32; off; off >>= 1) s += __shfl_xor(s, off);
  __shared__ float red[4];
  if ((t & 63) == 0) red[t >> 6] = s;
  __syncthreads();
  if (t == 0) out[0] = (red[0] + red[1] + red[2] + red[3]) * (1.0f / cBT);
}

extern "C" void kernel_launch(void* const* d_in, const int* in_sizes, int n_in,
                              void* d_out, int out_size, void* d_ws, size_t ws_size,
                              hipStream_t stream) {
  const int*   idx  = (const int*)d_in[0];
  const int*   tgt  = (const int*)d_in[1];
  const float* tok  = (const float*)d_in[2];
  const float* pos  = (const float*)d_in[3];
  const float* Wq   = (const float*)d_in[4];
  const float* Wk   = (const float*)d_in[5];
  const float* Wv   = (const float*)d_in[6];
  const float* Wo   = (const float*)d_in[7];
  const float* bo   = (const float*)d_in[8];
  const float* ln1g = (const float*)d_in[9];
  const float* ln1b = (const float*)d_in[10];
  const float* ln2g = (const float*)d_in[11];
  const float* ln2b = (const float*)d_in[12];
  const float* W1   = (const float*)d_in[13];
  const float* b1   = (const float*)d_in[14];
  const float* W2   = (const float*)d_in[15];
  const float* b2   = (const float*)d_in[16];
  const float* lnfg = (const float*)d_in[17];
  const float* lnfb = (const float*)d_in[18];
  const float* Wh   = (const float*)d_in[19];
  const float* bh   = (const float*)d_in[20];

  // --- d_out scratch plan (all dead before head GEMM overwrites d_out) ---
  char* ob = (char*)d_out;
  float* x    = (float*)ob;                          // [BT,E] f32, 16 MB
  u16* hb     = (u16*)(ob + (16u << 20));
  u16* qb     = (u16*)(ob + (24u << 20));            // q/k/v contiguous slabs
  u16* kb     = (u16*)(ob + (32u << 20));
  u16* vb     = (u16*)(ob + (40u << 20));
  u16* abuf   = (u16*)(ob + (48u << 20));
  u16* fbuf   = (u16*)(ob + (56u << 20));            // [BT,FF] bf16 -> ends 88M
  u16* W3T    = (u16*)(ob + (128u << 20));           // 12 x [3][E][E] (72MB) -> 200M
  u16* WoT    = (u16*)(ob + (200u << 20));           // 12 x [E][E]   (24MB) -> 224M
  u16* W1T    = (u16*)(ob + (224u << 20));           // 12 x [FF][E]  (96MB) -> 320M
  u16* W2T    = (u16*)(ob + (320u << 20));           // 12 x [E][FF]  (96MB) -> 416M
  // --- d_ws layout ---
  u16* hf     = (u16*)d_ws;                          // 8.39 MB
  float* nll  = (float*)((char*)d_ws + 8388608);
  u16* WheadT = (u16*)((char*)d_ws + 8404992);       // [cVp][E] bf16 (103.3 MB)
  const size_t whead_end = 8404992u + (size_t)cVp * cE * 2u;
  float* pmax = (float*)((char*)d_ws + whead_end);
  float* psum = (float*)((char*)d_ws + whead_end + (size_t)cBT * cNT * 4);
  const size_t ws_need = whead_end + 2u * (size_t)cBT * cNT * 4;
  const bool fast_head = ws_size >= ws_need;

  float* logits = (float*)d_out;
  float* loss = logits + (size_t)cBT * cV;

  const dim3 blk(256);
  const size_t e2 = (size_t)cE * cE, ef = (size_t)cE * cFF;

  // weight conversion (every call)
  k_cvt_t<<<dim3(16, 32, cL), blk, 0, stream>>>(Wq, W3T,          cE, cE, e2, 3 * e2);
  k_cvt_t<<<dim3(16, 32, cL), blk, 0, stream>>>(Wk, W3T + e2,     cE, cE, e2, 3 * e2);
  k_cvt_t<<<dim3(16, 32, cL), blk, 0, stream>>>(Wv, W3T + 2 * e2, cE, cE, e2, 3 * e2);
  k_cvt_t<<<dim3(16, 32, cL), blk, 0, stream>>>(Wo, WoT, cE, cE, e2, e2);
  k_cvt_t<<<dim3(64, 32, cL), blk, 0, stream>>>(W1, W1T, cE, cFF, ef, ef);
  k_cvt_t<<<dim3(16, 128, cL), blk, 0, stream>>>(W2, W2T, cFF, cE, ef, ef);
  if (fast_head)
    k_cvt_t<<<dim3(cVp / 64, 32, 1), blk, 0, stream>>>(Wh, WheadT, cE, cV, 0, 0);

  k_embed<<<dim3(cBT), blk, 0, stream>>>(idx, tok, pos, x);
  for (int l = 0; l < cL; ++l) {
    k_ln<<<dim3(cBT), blk, 0, stream>>>(x, ln1g + l * cE, ln1b + l * cE, hb);
    k_gemm2<0><<<dim3(32 * 12), dim3(512), 0, stream>>>(hb, W3T + l * 3 * e2,
        nullptr, qb, nullptr, cE, 3072, 0, 32, nullptr, nullptr);
    k_attn<<<dim3(8, 64), dim3(512), 0, stream>>>(qb, kb, vb, abuf);
    k_gemm_s<<<dim3(512), blk, 0, stream>>>(abuf, WoT + l * e2, bo + l * cE, x, cE, cE, 64);
    k_ln<<<dim3(cBT), blk, 0, stream>>>(x, ln2g + l * cE, ln2b + l * cE, hb);
    k_gemm2<2><<<dim3(32 * 16), dim3(512), 0, stream>>>(hb, W1T + l * ef,
        b1 + l * cFF, fbuf, nullptr, cE, cFF, 0, 32, nullptr, nullptr);
    k_gemm_s<<<dim3(512), blk, 0, stream>>>(fbuf, W2T + l * ef, b2 + l * cE, x, cFF, cE, 64);
  }
  k_ln<<<dim3(cBT), blk, 0, stream>>>(x, lnfg, lnfb, hf);
  if (fast_head) {
    k_gemm2<3><<<dim3(32 * cNT), dim3(512), 0, stream>>>(hf, WheadT, bh,
        nullptr, logits, cE, cV, cNT, 32, pmax, psum);
    k_nll2<<<dim3(cBT / 4), blk, 0, stream>>>(pmax, psum, logits, tgt, nll, cNT);
  } else {
    k_gemm_legacy3<<<dim3(393, 32), blk, 0, stream>>>(hf, Wh, bh, logits, cBT, cV, cE);
    k_nll<<<dim3(cBT), blk, 0, stream>>>(logits, tgt, nll);
  }
  k_loss<<<dim3(1), blk, 0, stream>>>(nll, loss);
}

// Round 14
// 3961.427 us; speedup vs baseline: 1.0988x; 1.0400x over previous
//
#include <hip/hip_runtime.h>
#include <cstdint>
#include <cstddef>

typedef unsigned short u16;
typedef __bf16 bf16x8 __attribute__((ext_vector_type(8)));
typedef float f32x4 __attribute__((ext_vector_type(4)));
typedef unsigned short u16x8 __attribute__((ext_vector_type(8)));
typedef unsigned short u16x4 __attribute__((ext_vector_type(4)));

constexpr int cV  = 50257;
constexpr int cVp = 50432;      // padded to 256
constexpr int cNT = cVp / 256;  // 197 head n-tiles
constexpr int cT  = 1024;
constexpr int cE  = 1024;
constexpr int cL  = 12;
constexpr int cFF = 4096;
constexpr int cBT = 4096;       // B*T

__device__ __forceinline__ u16 f2bf(float f) {
  union { float f; unsigned u; } x; x.f = f;
  unsigned r = x.u + 0x7fffu + ((x.u >> 16) & 1u);   // RNE
  return (u16)(r >> 16);
}

// async global->LDS, 16B per lane. dest must be linear in lane order.
__device__ __forceinline__ void gload16(const void* g, void* l) {
  __builtin_amdgcn_global_load_lds(
      (const __attribute__((address_space(1))) void*)g,
      (__attribute__((address_space(3))) void*)l, 16, 0, 0);
}

// XOR swizzle for 128B-wide LDS rows (attn): permute 16B chunks within row.
__device__ __forceinline__ int swzoff(int row, int chunk) {
  return ((chunk ^ (row & 7) ^ ((row >> 3) & 7)) << 4);
}

// bijective XCD-chunk swizzle for grids with nwg % 8 == 0 (k_gemm_s only)
__device__ __forceinline__ int xcd_swz(int id, int nwg) {
  if ((nwg & 7) == 0) { const int q = nwg >> 3; return (id & 7) * q + (id >> 3); }
  return id;
}

// ---------------- embedding ----------------
__global__ __launch_bounds__(256) void k_embed(const int* __restrict__ idx,
    const float* __restrict__ tok, const float* __restrict__ pos,
    float* __restrict__ x) {
  const int row = blockIdx.x;
  const int t = row & (cT - 1);
  const int tk = idx[row];
  const float4* tv = (const float4*)(tok + (size_t)tk * cE);
  const float4* pv = (const float4*)(pos + (size_t)t * cE);
  float4* xv = (float4*)(x + (size_t)row * cE);
  const int i = threadIdx.x;
  float4 a = tv[i];
  float4 p = pv[i];
  a.x += p.x; a.y += p.y; a.z += p.z; a.w += p.w;
  xv[i] = a;
}

// ---------------- layernorm (f32 in -> bf16 out) ----------------
__global__ __launch_bounds__(256) void k_ln(const float* __restrict__ x,
    const float* __restrict__ gw, const float* __restrict__ bw,
    u16* __restrict__ out) {
  const int row = blockIdx.x;
  const int t = threadIdx.x;
  const float4 v = ((const float4*)(x + (size_t)row * cE))[t];
  float s1 = v.x + v.y + v.z + v.w;
  float s2 = v.x * v.x + v.y * v.y + v.z * v.z + v.w * v.w;
  #pragma unroll
  for (int off = 32; off; off >>= 1) {
    s1 += __shfl_xor(s1, off);
    s2 += __shfl_xor(s2, off);
  }
  __shared__ float red[8];
  const int wid = t >> 6;
  if ((t & 63) == 0) { red[wid] = s1; red[4 + wid] = s2; }
  __syncthreads();
  s1 = red[0] + red[1] + red[2] + red[3];
  s2 = red[4] + red[5] + red[6] + red[7];
  const float mean = s1 * (1.0f / cE);
  const float var = s2 * (1.0f / cE) - mean * mean;
  const float rs = rsqrtf(var + 1e-5f);
  const float4 g4 = ((const float4*)gw)[t];
  const float4 b4 = ((const float4*)bw)[t];
  u16x4 o;
  o[0] = f2bf((v.x - mean) * rs * g4.x + b4.x);
  o[1] = f2bf((v.y - mean) * rs * g4.y + b4.y);
  o[2] = f2bf((v.z - mean) * rs * g4.z + b4.z);
  o[3] = f2bf((v.w - mean) * rs * g4.w + b4.w);
  *(u16x4*)(out + (size_t)row * cE + t * 4) = o;
}

// ------- weight convert+transpose: f32[K][N] -> bf16[N][K], vectorized -------
__global__ __launch_bounds__(256) void k_cvt_t(const float* __restrict__ src,
    u16* __restrict__ dst, int K, int Nsrc, size_t sstride, size_t dstride) {
  __shared__ float tile[32][65];
  const float* s = src + blockIdx.z * sstride;
  u16* d = dst + blockIdx.z * dstride;
  const int n0 = blockIdx.x * 64, k0 = blockIdx.y * 32;
  const int t = threadIdx.x;
  #pragma unroll
  for (int p = 0; p < 2; ++p) {
    const int li = p * 256 + t;
    const int k = li >> 4;            // 0..31
    const int n4 = (li & 15) * 4;     // 0..60
    const float* sp = s + (size_t)(k0 + k) * Nsrc + n0 + n4;
    if ((n0 + n4 + 3 < Nsrc) && ((((size_t)(k0 + k) * Nsrc + n0 + n4) & 3) == 0)) {
      const float4 f = *(const float4*)sp;
      tile[k][n4] = f.x; tile[k][n4 + 1] = f.y;
      tile[k][n4 + 2] = f.z; tile[k][n4 + 3] = f.w;
    } else {
      #pragma unroll
      for (int i = 0; i < 4; ++i)
        tile[k][n4 + i] = (n0 + n4 + i < Nsrc) ? sp[i] : 0.0f;
    }
  }
  __syncthreads();
  #pragma unroll
  for (int p = 0; p < 2; ++p) {
    const int si = p * 256 + t;
    const int n = si >> 3;            // 0..63
    const int k4 = (si & 7) * 4;      // 0..28
    u16x4 o;
    #pragma unroll
    for (int i = 0; i < 4; ++i) o[i] = f2bf(tile[k4 + i][n]);
    *(u16x4*)(d + (size_t)(n0 + n) * K + k0 + k4) = o;
  }
}

// ============== 128x256 GEMM, BK=32, 2 blocks/CU (round-11 best) ==============
// Plateau established (rounds 6-13): 24-28% MfmaUtil across 5 schedule/tile
// variants at K=1024; this is the simplest best one (651us head).
// (512,4): no spill (round-9 lesson). Plain stores (round-8 NT lesson).
// No pinning (m141). One __syncthreads per K-tile; stage(t+1) issued first.
template<int EPI>
__global__ __launch_bounds__(512, 4) void k_gemm2(
    const u16* __restrict__ A, const u16* __restrict__ Bt,
    const float* __restrict__ bias, u16* __restrict__ obf,
    float* __restrict__ of, int K, int Nout, int ntile, int mt,
    float* __restrict__ pm, float* __restrict__ ps) {
  __shared__ __align__(16) char smem[49152];
  const int tid = threadIdx.x;
  const int lane = tid & 63;
  const int wid = tid >> 6;
  const int wg = (int)blockIdx.x;
  const int bm = wg % mt;            // bm-fast: all CUs sweep same B panel
  const int bn = wg / mt;
  const int wm = wid >> 2, wn = wid & 3;
  const int l15 = lane & 15, lg = lane >> 4;

  f32x4 acc[4][4];
  #pragma unroll
  for (int i = 0; i < 4; ++i)
    #pragma unroll
    for (int j = 0; j < 4; ++j) { f32x4 z = {0.f,0.f,0.f,0.f}; acc[i][j] = z; }

  const u16* Ab = A + (size_t)(bm * 128) * K;
  const u16* Bb = Bt + (size_t)(bn * 256) * K;
  const int nt = K >> 5;

  auto stage = [&](int t) {
    char* buf = smem + ((t & 1) ? 24576 : 0);
    const int kt = t << 5;
    {
      const int r = tid >> 2, c = tid & 3;
      gload16(Ab + (size_t)r * K + kt + ((c ^ ((r >> 1) & 3)) << 3),
              buf + tid * 16);
    }
    #pragma unroll
    for (int p = 0; p < 2; ++p) {
      const int L = p * 512 + tid;
      const int r = L >> 2, c = L & 3;
      gload16(Bb + (size_t)r * K + kt + ((c ^ ((r >> 1) & 3)) << 3),
              buf + 8192 + L * 16);
    }
  };

  stage(0);
  for (int t = 0; t < nt; ++t) {
    __syncthreads();                     // tile t landed; readers of t-1 done
    if (t + 1 < nt) stage(t + 1);        // overlap loads with compute(t)
    char* cs = smem + ((t & 1) ? 24576 : 0);
    const char* csB = cs + 8192;
    bf16x8 af[4], bfr[4];
    #pragma unroll
    for (int mi = 0; mi < 4; ++mi) {
      const int row = wm * 64 + mi * 16 + l15;
      af[mi] = *(const bf16x8*)(cs + row * 64 + ((lg ^ ((row >> 1) & 3)) << 4));
    }
    #pragma unroll
    for (int ni = 0; ni < 4; ++ni) {
      const int row = wn * 64 + ni * 16 + l15;
      bfr[ni] = *(const bf16x8*)(csB + row * 64 + ((lg ^ ((row >> 1) & 3)) << 4));
    }
    #pragma unroll
    for (int ni = 0; ni < 4; ++ni)
      #pragma unroll
      for (int mi = 0; mi < 4; ++mi)
        acc[mi][ni] = __builtin_amdgcn_mfma_f32_16x16x32_bf16(af[mi], bfr[ni], acc[mi][ni], 0, 0, 0);
  }

  // ---- epilogue ----
  if constexpr (EPI == 3) {
    __syncthreads();                      // repurpose smem
    float* pb = (float*)smem;             // [128][4][2]
    #pragma unroll
    for (int mi = 0; mi < 4; ++mi) {
      const int grow = bm * 128 + wm * 64 + mi * 16 + lg * 4;
      float rm[4];
      #pragma unroll
      for (int r = 0; r < 4; ++r) rm[r] = -1e30f;
      #pragma unroll
      for (int ni = 0; ni < 4; ++ni) {
        const int gcol = bn * 256 + wn * 64 + ni * 16 + l15;
        const bool ok = gcol < Nout;
        const float bb = ok ? bias[gcol] : 0.0f;
        #pragma unroll
        for (int r = 0; r < 4; ++r) {
          const float v = ok ? (acc[mi][ni][r] + bb) : -1e30f;
          acc[mi][ni][r] = v;
          if (ok) of[(size_t)(grow + r) * Nout + gcol] = v;
          rm[r] = fmaxf(rm[r], v);
        }
      }
      #pragma unroll
      for (int r = 0; r < 4; ++r) {
        float m = rm[r];
        #pragma unroll
        for (int off = 1; off < 16; off <<= 1) m = fmaxf(m, __shfl_xor(m, off));
        float s = 0.f;
        #pragma unroll
        for (int ni = 0; ni < 4; ++ni) s += __expf(acc[mi][ni][r] - m);
        #pragma unroll
        for (int off = 1; off < 16; off <<= 1) s += __shfl_xor(s, off);
        if (l15 == 0) {
          const int lrow = wm * 64 + mi * 16 + lg * 4 + r;
          pb[(lrow * 4 + wn) * 2] = m;
          pb[(lrow * 4 + wn) * 2 + 1] = s;
        }
      }
    }
    __syncthreads();
    if (tid < 128) {
      float m = -1e30f, s = 0.f;
      #pragma unroll
      for (int q = 0; q < 4; ++q) {
        const float m2 = pb[(tid * 4 + q) * 2];
        const float s2 = pb[(tid * 4 + q) * 2 + 1];
        const float M = fmaxf(m, m2);
        s = s * __expf(m - M) + s2 * __expf(m2 - M);
        m = M;
      }
      const size_t grow = (size_t)(bm * 128 + tid);
      pm[grow * ntile + bn] = m;
      ps[grow * ntile + bn] = s;
    }
  } else {
    #pragma unroll
    for (int mi = 0; mi < 4; ++mi) {
      const int grow = bm * 128 + wm * 64 + mi * 16 + lg * 4;
      #pragma unroll
      for (int ni = 0; ni < 4; ++ni) {
        const int gcol = bn * 256 + wn * 64 + ni * 16 + l15;
        #pragma unroll
        for (int r = 0; r < 4; ++r) {
          const float a = acc[mi][ni][r];
          if constexpr (EPI == 0) {
            obf[(size_t)(gcol >> 10) * 4194304 + (size_t)(grow + r) * 1024 + (gcol & 1023)] = f2bf(a);
          } else {
            const float gv = a + bias[gcol];
            obf[(size_t)(grow + r) * Nout + gcol] = f2bf(0.5f * gv * (1.0f + erff(gv * 0.70710678118f)));
          }
        }
      }
    }
  }
}

// ------- small-M pipelined GEMM: 64x128 tile, BK=64, residual += -------
__global__ __launch_bounds__(256) void k_gemm_s(
    const u16* __restrict__ A, const u16* __restrict__ Bt,
    const float* __restrict__ bias, float* __restrict__ of,
    int K, int Nout, int mt) {
  __shared__ __align__(16) char smem[49152];
  const int tid = threadIdx.x;
  const int lane = tid & 63;
  const int wid = tid >> 6;
  const int wg = xcd_swz((int)blockIdx.x, (int)gridDim.x);
  const int bm = wg % mt;
  const int bn = wg / mt;
  const int wr = wid >> 1, wc = wid & 1;
  const int l15 = lane & 15, lg = lane >> 4;

  f32x4 acc[2][4];
  #pragma unroll
  for (int i = 0; i < 2; ++i)
    #pragma unroll
    for (int j = 0; j < 4; ++j) { f32x4 z = {0.f,0.f,0.f,0.f}; acc[i][j] = z; }

  const u16* Ab = A + (size_t)(bm * 64) * K;
  const u16* Bb = Bt + (size_t)(bn * 128) * K;
  const int nt = K >> 6;

  auto stage = [&](int t, char* buf) {
    const int kt = (t < nt ? t : nt - 1) << 6;
    #pragma unroll
    for (int p = 0; p < 2; ++p) {
      const int L = p * 256 + tid;
      const int row = L >> 3, cc = L & 7;
      gload16(Ab + (size_t)row * K + kt + ((cc ^ (row & 7)) << 3), buf + L * 16);
    }
    #pragma unroll
    for (int p = 0; p < 4; ++p) {
      const int L = p * 256 + tid;
      const int row = L >> 3, cc = L & 7;
      gload16(Bb + (size_t)row * K + kt + ((cc ^ (row & 7)) << 3), buf + 8192 + L * 16);
    }
  };
  stage(0, smem);
  stage(1, smem + 24576);

  for (int t = 0; t < nt; ++t) {
    char* cs = smem + ((t & 1) ? 24576 : 0);
    const char* csB = cs + 8192;
    asm volatile("s_waitcnt vmcnt(6)" ::: "memory");
    __builtin_amdgcn_s_barrier();

    bf16x8 af[2][2], bfr[4][2];
    #pragma unroll
    for (int mi = 0; mi < 2; ++mi) {
      const int row = wr * 32 + mi * 16 + l15;
      #pragma unroll
      for (int kk = 0; kk < 2; ++kk)
        af[mi][kk] = *(const bf16x8*)(cs + row * 128 + (((kk * 4 + lg) ^ (row & 7)) << 4));
    }
    #pragma unroll
    for (int ni = 0; ni < 4; ++ni) {
      const int row = wc * 64 + ni * 16 + l15;
      #pragma unroll
      for (int kk = 0; kk < 2; ++kk)
        bfr[ni][kk] = *(const bf16x8*)(csB + row * 128 + (((kk * 4 + lg) ^ (row & 7)) << 4));
    }
    __builtin_amdgcn_sched_barrier(0);
    __builtin_amdgcn_s_setprio(1);
    #pragma unroll
    for (int ni = 0; ni < 4; ++ni)
      #pragma unroll
      for (int mi = 0; mi < 2; ++mi)
        acc[mi][ni] = __builtin_amdgcn_mfma_f32_16x16x32_bf16(af[mi][0], bfr[ni][0], acc[mi][ni], 0, 0, 0);
    __builtin_amdgcn_s_setprio(0);
    __builtin_amdgcn_sched_barrier(0);
    asm volatile("s_waitcnt lgkmcnt(0)" ::: "memory");
    __builtin_amdgcn_sched_barrier(0);
    __builtin_amdgcn_s_barrier();

    stage(t + 2, cs);
    __builtin_amdgcn_sched_barrier(0);
    __builtin_amdgcn_s_setprio(1);
    #pragma unroll
    for (int ni = 0; ni < 4; ++ni)
      #pragma unroll
      for (int mi = 0; mi < 2; ++mi)
        acc[mi][ni] = __builtin_amdgcn_mfma_f32_16x16x32_bf16(af[mi][1], bfr[ni][1], acc[mi][ni], 0, 0, 0);
    __builtin_amdgcn_s_setprio(0);
    __builtin_amdgcn_sched_barrier(0);
  }
  asm volatile("s_waitcnt vmcnt(0)" ::: "memory");

  #pragma unroll
  for (int mi = 0; mi < 2; ++mi) {
    const int grow = bm * 64 + wr * 32 + mi * 16 + lg * 4;
    #pragma unroll
    for (int ni = 0; ni < 4; ++ni) {
      const int gcol = bn * 128 + wc * 64 + ni * 16 + l15;
      #pragma unroll
      for (int r = 0; r < 4; ++r)
        of[(size_t)(grow + r) * Nout + gcol] += acc[mi][ni][r] + bias[gcol];
    }
  }
}

// ---------------- legacy head GEMM (f32 B, used only if d_ws too small) ----------------
__global__ __launch_bounds__(256) void k_gemm_legacy3(
    const u16* __restrict__ A, const float* __restrict__ B0,
    const float* __restrict__ bias, float* __restrict__ of,
    int M, int N, int K) {
  __shared__ u16 Al[128 * 32];
  __shared__ u16 Bl[32 * 128];
  const int tid = threadIdx.x;
  const int lane = tid & 63;
  const int wid = tid >> 6;
  const int bn = blockIdx.x;
  const int bm = blockIdx.y;
  const int wr = wid >> 1, wc = wid & 1;
  const int l15 = lane & 15, lg = lane >> 4;
  f32x4 acc[4][4];
  #pragma unroll
  for (int i = 0; i < 4; ++i)
    #pragma unroll
    for (int j = 0; j < 4; ++j) { f32x4 z = {0.f,0.f,0.f,0.f}; acc[i][j] = z; }
  const u16* Abase = A + (size_t)(bm * 128) * K;
  const int ar0 = tid >> 2;
  const int ac0 = (tid & 3) * 8;
  const int brow = tid >> 3;
  const int bc0 = (tid & 7) * 16;
  for (int kt = 0; kt < K; kt += 32) {
    *(u16x8*)(Al + ar0 * 32 + ac0) =
        *(const u16x8*)(Abase + (size_t)ar0 * K + kt + ac0);
    *(u16x8*)(Al + (ar0 + 64) * 32 + ac0) =
        *(const u16x8*)(Abase + (size_t)(ar0 + 64) * K + kt + ac0);
    {
      const float* bsrc = B0 + (size_t)(kt + brow) * N + bn * 128 + bc0;
      alignas(16) u16 tmp[16];
      const int colbase = bn * 128 + bc0;
      #pragma unroll
      for (int q = 0; q < 16; ++q)
        tmp[q] = f2bf((colbase + q < N) ? bsrc[q] : 0.0f);
      *(u16x8*)(Bl + brow * 128 + bc0) = *(const u16x8*)tmp;
      *(u16x8*)(Bl + brow * 128 + bc0 + 8) = *(const u16x8*)(tmp + 8);
    }
    __syncthreads();
    bf16x8 af[4];
    #pragma unroll
    for (int mi = 0; mi < 4; ++mi)
      af[mi] = *(const bf16x8*)(Al + (wr * 64 + mi * 16 + l15) * 32 + lg * 8);
    #pragma unroll
    for (int ni = 0; ni < 4; ++ni) {
      u16x8 tv;
      #pragma unroll
      for (int i = 0; i < 8; ++i)
        tv[i] = Bl[(lg * 8 + i) * 128 + wc * 64 + ni * 16 + l15];
      const bf16x8 bfr = __builtin_bit_cast(bf16x8, tv);
      #pragma unroll
      for (int mi = 0; mi < 4; ++mi)
        acc[mi][ni] = __builtin_amdgcn_mfma_f32_16x16x32_bf16(af[mi], bfr, acc[mi][ni], 0, 0, 0);
    }
    __syncthreads();
  }
  #pragma unroll
  for (int mi = 0; mi < 4; ++mi) {
    const int grow = bm * 128 + wr * 64 + mi * 16 + lg * 4;
    #pragma unroll
    for (int ni = 0; ni < 4; ++ni) {
      const int gcol = bn * 128 + wc * 64 + ni * 16 + l15;
      #pragma unroll
      for (int r = 0; r < 4; ++r)
        if (gcol < N) of[(size_t)(grow + r) * N + gcol] = acc[mi][ni][r] + bias[gcol];
    }
  }
}

// ------ causal flash attention: 4 q-tiles (256 rows) per block, 8 waves ------
// grid (T/256, B*H), 512 thr. Wave w owns TWO 16-row q-groups g=0,1 at
// qwr_g = bx*256 + g*128 + w*16 (all state duplicated per group). K/V staged
// ONCE per kv-tile for all 256 q-rows: staging + V-transpose VALU amortized
// 4x vs the 64-row version, 2x vs round-11. Causal skip is wave-uniform per
// group; all threads hit both barriers.
__global__ __launch_bounds__(512, 2) void k_attn(
    const u16* __restrict__ qg, const u16* __restrict__ kg,
    const u16* __restrict__ vg, u16* __restrict__ og) {
  __shared__ u16 Kl[64 * 64];
  __shared__ u16 Vt[64 * 64];
  __shared__ u16 Pl[8][2][16 * 64];   // 32 KB
  const int tid = threadIdx.x;
  const int lane = tid & 63;
  const int w = tid >> 6;            // 0..7
  const int bx = blockIdx.x;         // 0..T/256-1
  const int bh = blockIdx.y;
  const int b = bh >> 4, h = bh & 15;
  const int l15 = lane & 15, lg = lane >> 4;
  char* KlB = (char*)Kl;
  char* VtB = (char*)Vt;

  int qwr[2], diagkt[2];
  size_t qrow0[2];
  bf16x8 aq[2][2];
  #pragma unroll
  for (int g = 0; g < 2; ++g) {
    qwr[g] = bx * 256 + g * 128 + w * 16;
    diagkt[g] = qwr[g] >> 6;
    qrow0[g] = (size_t)b * cT + qwr[g];
    #pragma unroll
    for (int c = 0; c < 2; ++c)
      aq[g][c] = *(const bf16x8*)(qg + (qrow0[g] + l15) * cE + h * 64 + c * 32 + lg * 8);
  }

  f32x4 acco[2][4];
  float mrun[2][4], lrun[2][4];
  #pragma unroll
  for (int g = 0; g < 2; ++g) {
    #pragma unroll
    for (int j = 0; j < 4; ++j) { f32x4 z = {0.f,0.f,0.f,0.f}; acco[g][j] = z; }
    #pragma unroll
    for (int r = 0; r < 4; ++r) { mrun[g][r] = -1e30f; lrun[g][r] = 0.f; }
  }

  const int ktmax = 4 * bx + 3;
  for (int kt = 0; kt <= ktmax; ++kt) {
    const size_t krow0 = (size_t)b * cT + kt * 64;
    {
      const int rr = tid >> 3, c8 = (tid & 7) * 8;   // 512 thr cover 64x64
      *(u16x8*)(KlB + rr * 128 + swzoff(rr, c8 >> 3)) =
          *(const u16x8*)(kg + (krow0 + rr) * cE + h * 64 + c8);
      const u16x8 vv = *(const u16x8*)(vg + (krow0 + rr) * cE + h * 64 + c8);
      #pragma unroll
      for (int i = 0; i < 8; ++i)
        *(u16*)(VtB + (c8 + i) * 128 + swzoff(c8 + i, rr >> 3) + (rr & 7) * 2) = vv[i];
    }
    __syncthreads();

    #pragma unroll
    for (int g = 0; g < 2; ++g) {
      if (kt <= diagkt[g]) {                 // wave-uniform causal skip
        char* PlB = (char*)(Pl[w][g]);
        f32x4 s[4];
        #pragma unroll
        for (int j = 0; j < 4; ++j) { f32x4 z = {0.f,0.f,0.f,0.f}; s[j] = z; }
        #pragma unroll
        for (int c = 0; c < 2; ++c) {
          #pragma unroll
          for (int j = 0; j < 4; ++j) {
            const int n = j * 16 + l15;
            const bf16x8 kb2 = *(const bf16x8*)(KlB + n * 128 + swzoff(n, c * 4 + lg));
            s[j] = __builtin_amdgcn_mfma_f32_16x16x32_bf16(aq[g][c], kb2, s[j], 0, 0, 0);
          }
        }

        float sv[4][4];
        const bool diag = (kt == diagkt[g]);
        #pragma unroll
        for (int j = 0; j < 4; ++j)
          #pragma unroll
          for (int r = 0; r < 4; ++r) {
            float xs = s[j][r] * 0.125f;
            if (diag && (kt * 64 + j * 16 + l15) > (qwr[g] + lg * 4 + r)) xs = -1e30f;
            sv[j][r] = xs;
          }

        float corr[4];
        #pragma unroll
        for (int r = 0; r < 4; ++r) {
          float mx = fmaxf(fmaxf(sv[0][r], sv[1][r]), fmaxf(sv[2][r], sv[3][r]));
          #pragma unroll
          for (int off = 1; off < 16; off <<= 1) mx = fmaxf(mx, __shfl_xor(mx, off));
          const float mnew = fmaxf(mrun[g][r], mx);
          corr[r] = __expf(mrun[g][r] - mnew);
          float rs = 0.f;
          #pragma unroll
          for (int j = 0; j < 4; ++j) {
            const float p = __expf(sv[j][r] - mnew);
            sv[j][r] = p;
            rs += p;
          }
          #pragma unroll
          for (int off = 1; off < 16; off <<= 1) rs += __shfl_xor(rs, off);
          lrun[g][r] = lrun[g][r] * corr[r] + rs;
          mrun[g][r] = mnew;
        }

        #pragma unroll
        for (int j = 0; j < 4; ++j)
          #pragma unroll
          for (int r = 0; r < 4; ++r) {
            const int qr = lg * 4 + r, kc = j * 16 + l15;
            *(u16*)(PlB + qr * 128 + swzoff(qr, kc >> 3) + (kc & 7) * 2) = f2bf(sv[j][r]);
            acco[g][j][r] *= corr[r];
          }

        #pragma unroll
        for (int c = 0; c < 2; ++c) {
          const bf16x8 pa = *(const bf16x8*)(PlB + l15 * 128 + swzoff(l15, c * 4 + lg));
          #pragma unroll
          for (int j = 0; j < 4; ++j) {
            const int n = j * 16 + l15;
            const bf16x8 vb2 = *(const bf16x8*)(VtB + n * 128 + swzoff(n, c * 4 + lg));
            acco[g][j] = __builtin_amdgcn_mfma_f32_16x16x32_bf16(pa, vb2, acco[g][j], 0, 0, 0);
          }
        }
      }
    }
    __syncthreads();
  }

  #pragma unroll
  for (int g = 0; g < 2; ++g)
    #pragma unroll
    for (int j = 0; j < 4; ++j)
      #pragma unroll
      for (int r = 0; r < 4; ++r)
        og[(qrow0[g] + lg * 4 + r) * cE + h * 64 + j * 16 + l15] =
            f2bf(acco[g][j][r] / lrun[g][r]);
}

// ---------------- NLL from per-tile partials ----------------
__global__ __launch_bounds__(256) void k_nll2(const float* __restrict__ pm,
    const float* __restrict__ ps, const float* __restrict__ logits,
    const int* __restrict__ tgt, float* __restrict__ nll, int NT) {
  const int row = blockIdx.x * 4 + (threadIdx.x >> 6);
  const int lane = threadIdx.x & 63;
  float m = -1e30f, s = 0.f;
  for (int i = lane; i < NT; i += 64) {
    const float m2 = pm[(size_t)row * NT + i];
    const float s2 = ps[(size_t)row * NT + i];
    const float M = fmaxf(m, m2);
    s = s * __expf(m - M) + s2 * __expf(m2 - M);
    m = M;
  }
  #pragma unroll
  for (int off = 1; off < 64; off <<= 1) {
    const float m2 = __shfl_xor(m, off);
    const float s2 = __shfl_xor(s, off);
    const float M = fmaxf(m, m2);
    s = s * __expf(m - M) + s2 * __expf(m2 - M);
    m = M;
  }
  if (lane == 0)
    nll[row] = logf(s) + m - logits[(size_t)row * cV + tgt[row]];
}

// ---------------- per-row NLL over V (fallback) ----------------
__global__ __launch_bounds__(256) void k_nll(const float* __restrict__ logits,
    const int* __restrict__ tgt, float* __restrict__ nll) {
  const int row = blockIdx.x;
  const float* lp = logits + (size_t)row * cV;
  const int t = threadIdx.x;
  __shared__ float red[8];
  const int wid = t >> 6, lane = t & 63;
  float mx = -1e30f;
  for (int i = t; i < cV; i += 256) mx = fmaxf(mx, lp[i]);
  #pragma unroll
  for (int off = 32; off; off >>= 1) mx = fmaxf(mx, __shfl_xor(mx, off));
  if (lane == 0) red[wid] = mx;
  __syncthreads();
  mx = fmaxf(fmaxf(red[0], red[1]), fmaxf(red[2], red[3]));
  float s = 0.f;
  for (int i = t; i < cV; i += 256) s += __expf(lp[i] - mx);
  #pragma unroll
  for (int off = 32; off; off >>= 1) s += __shfl_xor(s, off);
  if (lane == 0) red[4 + wid] = s;
  __syncthreads();
  if (t == 0) {
    s = red[4] + red[5] + red[6] + red[7];
    nll[row] = logf(s) + mx - lp[tgt[row]];
  }
}

__global__ __launch_bounds__(256) void k_loss(const float* __restrict__ nll,
    float* __restrict__ out) {
  const int t = threadIdx.x;
  float s = 0.f;
  for (int i = t; i < cBT; i += 256) s += nll[i];
  #pragma unroll
  for (int off = 32; off; off >>= 1) s += __shfl_xor(s, off);
  __shared__ float red[4];
  if ((t & 63) == 0) red[t >> 6] = s;
  __syncthreads();
  if (t == 0) out[0] = (red[0] + red[1] + red[2] + red[3]) * (1.0f / cBT);
}

extern "C" void kernel_launch(void* const* d_in, const int* in_sizes, int n_in,
                              void* d_out, int out_size, void* d_ws, size_t ws_size,
                              hipStream_t stream) {
  const int*   idx  = (const int*)d_in[0];
  const int*   tgt  = (const int*)d_in[1];
  const float* tok  = (const float*)d_in[2];
  const float* pos  = (const float*)d_in[3];
  const float* Wq   = (const float*)d_in[4];
  const float* Wk   = (const float*)d_in[5];
  const float* Wv   = (const float*)d_in[6];
  const float* Wo   = (const float*)d_in[7];
  const float* bo   = (const float*)d_in[8];
  const float* ln1g = (const float*)d_in[9];
  const float* ln1b = (const float*)d_in[10];
  const float* ln2g = (const float*)d_in[11];
  const float* ln2b = (const float*)d_in[12];
  const float* W1   = (const float*)d_in[13];
  const float* b1   = (const float*)d_in[14];
  const float* W2   = (const float*)d_in[15];
  const float* b2   = (const float*)d_in[16];
  const float* lnfg = (const float*)d_in[17];
  const float* lnfb = (const float*)d_in[18];
  const float* Wh   = (const float*)d_in[19];
  const float* bh   = (const float*)d_in[20];

  // --- d_out scratch plan (all dead before head GEMM overwrites d_out) ---
  char* ob = (char*)d_out;
  float* x    = (float*)ob;                          // [BT,E] f32, 16 MB
  u16* hb     = (u16*)(ob + (16u << 20));
  u16* qb     = (u16*)(ob + (24u << 20));            // q/k/v contiguous slabs
  u16* kb     = (u16*)(ob + (32u << 20));
  u16* vb     = (u16*)(ob + (40u << 20));
  u16* abuf   = (u16*)(ob + (48u << 20));
  u16* fbuf   = (u16*)(ob + (56u << 20));            // [BT,FF] bf16 -> ends 88M
  u16* W3T    = (u16*)(ob + (128u << 20));           // 12 x [3][E][E] (72MB) -> 200M
  u16* WoT    = (u16*)(ob + (200u << 20));           // 12 x [E][E]   (24MB) -> 224M
  u16* W1T    = (u16*)(ob + (224u << 20));           // 12 x [FF][E]  (96MB) -> 320M
  u16* W2T    = (u16*)(ob + (320u << 20));           // 12 x [E][FF]  (96MB) -> 416M
  // --- d_ws layout ---
  u16* hf     = (u16*)d_ws;                          // 8.39 MB
  float* nll  = (float*)((char*)d_ws + 8388608);
  u16* WheadT = (u16*)((char*)d_ws + 8404992);       // [cVp][E] bf16 (103.3 MB)
  const size_t whead_end = 8404992u + (size_t)cVp * cE * 2u;
  float* pmax = (float*)((char*)d_ws + whead_end);
  float* psum = (float*)((char*)d_ws + whead_end + (size_t)cBT * cNT * 4);
  const size_t ws_need = whead_end + 2u * (size_t)cBT * cNT * 4;
  const bool fast_head = ws_size >= ws_need;

  float* logits = (float*)d_out;
  float* loss = logits + (size_t)cBT * cV;

  const dim3 blk(256);
  const size_t e2 = (size_t)cE * cE, ef = (size_t)cE * cFF;

  // weight conversion (every call)
  k_cvt_t<<<dim3(16, 32, cL), blk, 0, stream>>>(Wq, W3T,          cE, cE, e2, 3 * e2);
  k_cvt_t<<<dim3(16, 32, cL), blk, 0, stream>>>(Wk, W3T + e2,     cE, cE, e2, 3 * e2);
  k_cvt_t<<<dim3(16, 32, cL), blk, 0, stream>>>(Wv, W3T + 2 * e2, cE, cE, e2, 3 * e2);
  k_cvt_t<<<dim3(16, 32, cL), blk, 0, stream>>>(Wo, WoT, cE, cE, e2, e2);
  k_cvt_t<<<dim3(64, 32, cL), blk, 0, stream>>>(W1, W1T, cE, cFF, ef, ef);
  k_cvt_t<<<dim3(16, 128, cL), blk, 0, stream>>>(W2, W2T, cFF, cE, ef, ef);
  if (fast_head)
    k_cvt_t<<<dim3(cVp / 64, 32, 1), blk, 0, stream>>>(Wh, WheadT, cE, cV, 0, 0);

  k_embed<<<dim3(cBT), blk, 0, stream>>>(idx, tok, pos, x);
  for (int l = 0; l < cL; ++l) {
    k_ln<<<dim3(cBT), blk, 0, stream>>>(x, ln1g + l * cE, ln1b + l * cE, hb);
    k_gemm2<0><<<dim3(32 * 12), dim3(512), 0, stream>>>(hb, W3T + l * 3 * e2,
        nullptr, qb, nullptr, cE, 3072, 0, 32, nullptr, nullptr);
    k_attn<<<dim3(4, 64), dim3(512), 0, stream>>>(qb, kb, vb, abuf);
    k_gemm_s<<<dim3(512), blk, 0, stream>>>(abuf, WoT + l * e2, bo + l * cE, x, cE, cE, 64);
    k_ln<<<dim3(cBT), blk, 0, stream>>>(x, ln2g + l * cE, ln2b + l * cE, hb);
    k_gemm2<2><<<dim3(32 * 16), dim3(512), 0, stream>>>(hb, W1T + l * ef,
        b1 + l * cFF, fbuf, nullptr, cE, cFF, 0, 32, nullptr, nullptr);
    k_gemm_s<<<dim3(512), blk, 0, stream>>>(fbuf, W2T + l * ef, b2 + l * cE, x, cFF, cE, 64);
  }
  k_ln<<<dim3(cBT), blk, 0, stream>>>(x, lnfg, lnfb, hf);
  if (fast_head) {
    k_gemm2<3><<<dim3(32 * cNT), dim3(512), 0, stream>>>(hf, WheadT, bh,
        nullptr, logits, cE, cV, cNT, 32, pmax, psum);
    k_nll2<<<dim3(cBT / 4), blk, 0, stream>>>(pmax, psum, logits, tgt, nll, cNT);
  } else {
    k_gemm_legacy3<<<dim3(393, 32), blk, 0, stream>>>(hf, Wh, bh, logits, cBT, cV, cE);
    k_nll<<<dim3(cBT), blk, 0, stream>>>(logits, tgt, nll);
  }
  k_loss<<<dim3(1), blk, 0, stream>>>(nll, loss);
}

// Round 15
// 3876.743 us; speedup vs baseline: 1.1228x; 1.0218x over previous
//
#include <hip/hip_runtime.h>
#include <cstdint>
#include <cstddef>

typedef unsigned short u16;
typedef __bf16 bf16x8 __attribute__((ext_vector_type(8)));
typedef float f32x4 __attribute__((ext_vector_type(4)));
typedef unsigned short u16x8 __attribute__((ext_vector_type(8)));
typedef unsigned short u16x4 __attribute__((ext_vector_type(4)));

constexpr int cV  = 50257;
constexpr int cVp = 50432;      // padded to 256
constexpr int cNT = cVp / 256;  // 197 head n-tiles
constexpr int cT  = 1024;
constexpr int cE  = 1024;
constexpr int cL  = 12;
constexpr int cFF = 4096;
constexpr int cBT = 4096;       // B*T

__device__ __forceinline__ u16 f2bf(float f) {
  union { float f; unsigned u; } x; x.f = f;
  unsigned r = x.u + 0x7fffu + ((x.u >> 16) & 1u);   // RNE
  return (u16)(r >> 16);
}
__device__ __forceinline__ float bf2f(u16 h) {
  union { unsigned u; float f; } z; z.u = ((unsigned)h) << 16; return z.f;
}

// async global->LDS, 16B per lane. dest must be linear in lane order.
__device__ __forceinline__ void gload16(const void* g, void* l) {
  __builtin_amdgcn_global_load_lds(
      (const __attribute__((address_space(1))) void*)g,
      (__attribute__((address_space(3))) void*)l, 16, 0, 0);
}

// XOR swizzle for 128B-wide LDS rows (attn): permute 16B chunks within row.
__device__ __forceinline__ int swzoff(int row, int chunk) {
  return ((chunk ^ (row & 7) ^ ((row >> 3) & 7)) << 4);
}

// bijective XCD-chunk swizzle for grids with nwg % 8 == 0 (k_gemm_s only)
__device__ __forceinline__ int xcd_swz(int id, int nwg) {
  if ((nwg & 7) == 0) { const int q = nwg >> 3; return (id & 7) * q + (id >> 3); }
  return id;
}

// ---------------- embedding: x(bf16) = tok_emb[idx] + pos_emb ----------------
__global__ __launch_bounds__(256) void k_embed(const int* __restrict__ idx,
    const float* __restrict__ tok, const float* __restrict__ pos,
    u16* __restrict__ x) {
  const int row = blockIdx.x;
  const int t = row & (cT - 1);
  const int tk = idx[row];
  const float4* tv = (const float4*)(tok + (size_t)tk * cE);
  const float4* pv = (const float4*)(pos + (size_t)t * cE);
  const int i = threadIdx.x;
  float4 a = tv[i];
  float4 p = pv[i];
  u16x4 o;
  o[0] = f2bf(a.x + p.x); o[1] = f2bf(a.y + p.y);
  o[2] = f2bf(a.z + p.z); o[3] = f2bf(a.w + p.w);
  ((u16x4*)(x + (size_t)row * cE))[i] = o;
}

// ---------------- layernorm (bf16 in -> bf16 out) ----------------
__global__ __launch_bounds__(256) void k_ln(const u16* __restrict__ x,
    const float* __restrict__ gw, const float* __restrict__ bw,
    u16* __restrict__ out) {
  const int row = blockIdx.x;
  const int t = threadIdx.x;
  const u16x4 v4 = ((const u16x4*)(x + (size_t)row * cE))[t];
  float v[4];
  #pragma unroll
  for (int i = 0; i < 4; ++i) v[i] = bf2f(v4[i]);
  float s1 = v[0] + v[1] + v[2] + v[3];
  float s2 = v[0]*v[0] + v[1]*v[1] + v[2]*v[2] + v[3]*v[3];
  #pragma unroll
  for (int off = 32; off; off >>= 1) {
    s1 += __shfl_xor(s1, off);
    s2 += __shfl_xor(s2, off);
  }
  __shared__ float red[8];
  const int wid = t >> 6;
  if ((t & 63) == 0) { red[wid] = s1; red[4 + wid] = s2; }
  __syncthreads();
  s1 = red[0] + red[1] + red[2] + red[3];
  s2 = red[4] + red[5] + red[6] + red[7];
  const float mean = s1 * (1.0f / cE);
  const float var = s2 * (1.0f / cE) - mean * mean;
  const float rs = rsqrtf(var + 1e-5f);
  const float4 g4 = ((const float4*)gw)[t];
  const float4 b4 = ((const float4*)bw)[t];
  u16x4 o;
  o[0] = f2bf((v[0] - mean) * rs * g4.x + b4.x);
  o[1] = f2bf((v[1] - mean) * rs * g4.y + b4.y);
  o[2] = f2bf((v[2] - mean) * rs * g4.z + b4.z);
  o[3] = f2bf((v[3] - mean) * rs * g4.w + b4.w);
  *(u16x4*)(out + (size_t)row * cE + t * 4) = o;
}

// ------- weight convert+transpose: f32[K][N] -> bf16[N][K], vectorized -------
__global__ __launch_bounds__(256) void k_cvt_t(const float* __restrict__ src,
    u16* __restrict__ dst, int K, int Nsrc, size_t sstride, size_t dstride) {
  __shared__ float tile[32][65];
  const float* s = src + blockIdx.z * sstride;
  u16* d = dst + blockIdx.z * dstride;
  const int n0 = blockIdx.x * 64, k0 = blockIdx.y * 32;
  const int t = threadIdx.x;
  #pragma unroll
  for (int p = 0; p < 2; ++p) {
    const int li = p * 256 + t;
    const int k = li >> 4;            // 0..31
    const int n4 = (li & 15) * 4;     // 0..60
    const float* sp = s + (size_t)(k0 + k) * Nsrc + n0 + n4;
    if ((n0 + n4 + 3 < Nsrc) && ((((size_t)(k0 + k) * Nsrc + n0 + n4) & 3) == 0)) {
      const float4 f = *(const float4*)sp;
      tile[k][n4] = f.x; tile[k][n4 + 1] = f.y;
      tile[k][n4 + 2] = f.z; tile[k][n4 + 3] = f.w;
    } else {
      #pragma unroll
      for (int i = 0; i < 4; ++i)
        tile[k][n4 + i] = (n0 + n4 + i < Nsrc) ? sp[i] : 0.0f;
    }
  }
  __syncthreads();
  #pragma unroll
  for (int p = 0; p < 2; ++p) {
    const int si = p * 256 + t;
    const int n = si >> 3;            // 0..63
    const int k4 = (si & 7) * 4;      // 0..28
    u16x4 o;
    #pragma unroll
    for (int i = 0; i < 4; ++i) o[i] = f2bf(tile[k4 + i][n]);
    *(u16x4*)(d + (size_t)(n0 + n) * K + k0 + k4) = o;
  }
}

// ============== 128x256 GEMM, BK=32, 2 blocks/CU (round-11 best) ==============
// GEMM plateau established (rounds 6-13): ~650 TF across 5 schedule/tile
// variants at K=1024 (LDS-BW bound); this is the simplest best one.
// (512,4): no spill (round-9 lesson). Plain stores (round-8 NT lesson).
// No pinning (m141). One __syncthreads per K-tile; stage(t+1) issued first.
template<int EPI>
__global__ __launch_bounds__(512, 4) void k_gemm2(
    const u16* __restrict__ A, const u16* __restrict__ Bt,
    const float* __restrict__ bias, u16* __restrict__ obf,
    float* __restrict__ of, int K, int Nout, int ntile, int mt,
    float* __restrict__ pm, float* __restrict__ ps) {
  __shared__ __align__(16) char smem[49152];
  const int tid = threadIdx.x;
  const int lane = tid & 63;
  const int wid = tid >> 6;
  const int wg = (int)blockIdx.x;
  const int bm = wg % mt;            // bm-fast: all CUs sweep same B panel
  const int bn = wg / mt;
  const int wm = wid >> 2, wn = wid & 3;
  const int l15 = lane & 15, lg = lane >> 4;

  f32x4 acc[4][4];
  #pragma unroll
  for (int i = 0; i < 4; ++i)
    #pragma unroll
    for (int j = 0; j < 4; ++j) { f32x4 z = {0.f,0.f,0.f,0.f}; acc[i][j] = z; }

  const u16* Ab = A + (size_t)(bm * 128) * K;
  const u16* Bb = Bt + (size_t)(bn * 256) * K;
  const int nt = K >> 5;

  auto stage = [&](int t) {
    char* buf = smem + ((t & 1) ? 24576 : 0);
    const int kt = t << 5;
    {
      const int r = tid >> 2, c = tid & 3;
      gload16(Ab + (size_t)r * K + kt + ((c ^ ((r >> 1) & 3)) << 3),
              buf + tid * 16);
    }
    #pragma unroll
    for (int p = 0; p < 2; ++p) {
      const int L = p * 512 + tid;
      const int r = L >> 2, c = L & 3;
      gload16(Bb + (size_t)r * K + kt + ((c ^ ((r >> 1) & 3)) << 3),
              buf + 8192 + L * 16);
    }
  };

  stage(0);
  for (int t = 0; t < nt; ++t) {
    __syncthreads();                     // tile t landed; readers of t-1 done
    if (t + 1 < nt) stage(t + 1);        // overlap loads with compute(t)
    char* cs = smem + ((t & 1) ? 24576 : 0);
    const char* csB = cs + 8192;
    bf16x8 af[4], bfr[4];
    #pragma unroll
    for (int mi = 0; mi < 4; ++mi) {
      const int row = wm * 64 + mi * 16 + l15;
      af[mi] = *(const bf16x8*)(cs + row * 64 + ((lg ^ ((row >> 1) & 3)) << 4));
    }
    #pragma unroll
    for (int ni = 0; ni < 4; ++ni) {
      const int row = wn * 64 + ni * 16 + l15;
      bfr[ni] = *(const bf16x8*)(csB + row * 64 + ((lg ^ ((row >> 1) & 3)) << 4));
    }
    #pragma unroll
    for (int ni = 0; ni < 4; ++ni)
      #pragma unroll
      for (int mi = 0; mi < 4; ++mi)
        acc[mi][ni] = __builtin_amdgcn_mfma_f32_16x16x32_bf16(af[mi], bfr[ni], acc[mi][ni], 0, 0, 0);
  }

  // ---- epilogue ----
  if constexpr (EPI == 3) {
    __syncthreads();                      // repurpose smem
    float* pb = (float*)smem;             // [128][4][2]
    #pragma unroll
    for (int mi = 0; mi < 4; ++mi) {
      const int grow = bm * 128 + wm * 64 + mi * 16 + lg * 4;
      float rm[4];
      #pragma unroll
      for (int r = 0; r < 4; ++r) rm[r] = -1e30f;
      #pragma unroll
      for (int ni = 0; ni < 4; ++ni) {
        const int gcol = bn * 256 + wn * 64 + ni * 16 + l15;
        const bool ok = gcol < Nout;
        const float bb = ok ? bias[gcol] : 0.0f;
        #pragma unroll
        for (int r = 0; r < 4; ++r) {
          const float v = ok ? (acc[mi][ni][r] + bb) : -1e30f;
          acc[mi][ni][r] = v;
          if (ok) of[(size_t)(grow + r) * Nout + gcol] = v;
          rm[r] = fmaxf(rm[r], v);
        }
      }
      #pragma unroll
      for (int r = 0; r < 4; ++r) {
        float m = rm[r];
        #pragma unroll
        for (int off = 1; off < 16; off <<= 1) m = fmaxf(m, __shfl_xor(m, off));
        float s = 0.f;
        #pragma unroll
        for (int ni = 0; ni < 4; ++ni) s += __expf(acc[mi][ni][r] - m);
        #pragma unroll
        for (int off = 1; off < 16; off <<= 1) s += __shfl_xor(s, off);
        if (l15 == 0) {
          const int lrow = wm * 64 + mi * 16 + lg * 4 + r;
          pb[(lrow * 4 + wn) * 2] = m;
          pb[(lrow * 4 + wn) * 2 + 1] = s;
        }
      }
    }
    __syncthreads();
    if (tid < 128) {
      float m = -1e30f, s = 0.f;
      #pragma unroll
      for (int q = 0; q < 4; ++q) {
        const float m2 = pb[(tid * 4 + q) * 2];
        const float s2 = pb[(tid * 4 + q) * 2 + 1];
        const float M = fmaxf(m, m2);
        s = s * __expf(m - M) + s2 * __expf(m2 - M);
        m = M;
      }
      const size_t grow = (size_t)(bm * 128 + tid);
      pm[grow * ntile + bn] = m;
      ps[grow * ntile + bn] = s;
    }
  } else {
    #pragma unroll
    for (int mi = 0; mi < 4; ++mi) {
      const int grow = bm * 128 + wm * 64 + mi * 16 + lg * 4;
      #pragma unroll
      for (int ni = 0; ni < 4; ++ni) {
        const int gcol = bn * 256 + wn * 64 + ni * 16 + l15;
        #pragma unroll
        for (int r = 0; r < 4; ++r) {
          const float a = acc[mi][ni][r];
          if constexpr (EPI == 0) {
            obf[(size_t)(gcol >> 10) * 4194304 + (size_t)(grow + r) * 1024 + (gcol & 1023)] = f2bf(a);
          } else {
            const float gv = a + bias[gcol];
            obf[(size_t)(grow + r) * Nout + gcol] = f2bf(0.5f * gv * (1.0f + erff(gv * 0.70710678118f)));
          }
        }
      }
    }
  }
}

// ------- small-M pipelined GEMM: 64x128 tile, BK=64, residual += (bf16 x) -------
__global__ __launch_bounds__(256) void k_gemm_s(
    const u16* __restrict__ A, const u16* __restrict__ Bt,
    const float* __restrict__ bias, u16* __restrict__ of,
    int K, int Nout, int mt) {
  __shared__ __align__(16) char smem[49152];
  const int tid = threadIdx.x;
  const int lane = tid & 63;
  const int wid = tid >> 6;
  const int wg = xcd_swz((int)blockIdx.x, (int)gridDim.x);
  const int bm = wg % mt;
  const int bn = wg / mt;
  const int wr = wid >> 1, wc = wid & 1;
  const int l15 = lane & 15, lg = lane >> 4;

  f32x4 acc[2][4];
  #pragma unroll
  for (int i = 0; i < 2; ++i)
    #pragma unroll
    for (int j = 0; j < 4; ++j) { f32x4 z = {0.f,0.f,0.f,0.f}; acc[i][j] = z; }

  const u16* Ab = A + (size_t)(bm * 64) * K;
  const u16* Bb = Bt + (size_t)(bn * 128) * K;
  const int nt = K >> 6;

  auto stage = [&](int t, char* buf) {
    const int kt = (t < nt ? t : nt - 1) << 6;
    #pragma unroll
    for (int p = 0; p < 2; ++p) {
      const int L = p * 256 + tid;
      const int row = L >> 3, cc = L & 7;
      gload16(Ab + (size_t)row * K + kt + ((cc ^ (row & 7)) << 3), buf + L * 16);
    }
    #pragma unroll
    for (int p = 0; p < 4; ++p) {
      const int L = p * 256 + tid;
      const int row = L >> 3, cc = L & 7;
      gload16(Bb + (size_t)row * K + kt + ((cc ^ (row & 7)) << 3), buf + 8192 + L * 16);
    }
  };
  stage(0, smem);
  stage(1, smem + 24576);

  for (int t = 0; t < nt; ++t) {
    char* cs = smem + ((t & 1) ? 24576 : 0);
    const char* csB = cs + 8192;
    asm volatile("s_waitcnt vmcnt(6)" ::: "memory");
    __builtin_amdgcn_s_barrier();

    bf16x8 af[2][2], bfr[4][2];
    #pragma unroll
    for (int mi = 0; mi < 2; ++mi) {
      const int row = wr * 32 + mi * 16 + l15;
      #pragma unroll
      for (int kk = 0; kk < 2; ++kk)
        af[mi][kk] = *(const bf16x8*)(cs + row * 128 + (((kk * 4 + lg) ^ (row & 7)) << 4));
    }
    #pragma unroll
    for (int ni = 0; ni < 4; ++ni) {
      const int row = wc * 64 + ni * 16 + l15;
      #pragma unroll
      for (int kk = 0; kk < 2; ++kk)
        bfr[ni][kk] = *(const bf16x8*)(csB + row * 128 + (((kk * 4 + lg) ^ (row & 7)) << 4));
    }
    __builtin_amdgcn_sched_barrier(0);
    __builtin_amdgcn_s_setprio(1);
    #pragma unroll
    for (int ni = 0; ni < 4; ++ni)
      #pragma unroll
      for (int mi = 0; mi < 2; ++mi)
        acc[mi][ni] = __builtin_amdgcn_mfma_f32_16x16x32_bf16(af[mi][0], bfr[ni][0], acc[mi][ni], 0, 0, 0);
    __builtin_amdgcn_s_setprio(0);
    __builtin_amdgcn_sched_barrier(0);
    asm volatile("s_waitcnt lgkmcnt(0)" ::: "memory");
    __builtin_amdgcn_sched_barrier(0);
    __builtin_amdgcn_s_barrier();

    stage(t + 2, cs);
    __builtin_amdgcn_sched_barrier(0);
    __builtin_amdgcn_s_setprio(1);
    #pragma unroll
    for (int ni = 0; ni < 4; ++ni)
      #pragma unroll
      for (int mi = 0; mi < 2; ++mi)
        acc[mi][ni] = __builtin_amdgcn_mfma_f32_16x16x32_bf16(af[mi][1], bfr[ni][1], acc[mi][ni], 0, 0, 0);
    __builtin_amdgcn_s_setprio(0);
    __builtin_amdgcn_sched_barrier(0);
  }
  asm volatile("s_waitcnt vmcnt(0)" ::: "memory");

  #pragma unroll
  for (int mi = 0; mi < 2; ++mi) {
    const int grow = bm * 64 + wr * 32 + mi * 16 + lg * 4;
    #pragma unroll
    for (int ni = 0; ni < 4; ++ni) {
      const int gcol = bn * 128 + wc * 64 + ni * 16 + l15;
      #pragma unroll
      for (int r = 0; r < 4; ++r) {
        u16* xp = of + (size_t)(grow + r) * Nout + gcol;
        *xp = f2bf(bf2f(*xp) + acc[mi][ni][r] + bias[gcol]);
      }
    }
  }
}

// ---------------- legacy head GEMM (f32 B, used only if d_ws too small) ----------------
__global__ __launch_bounds__(256) void k_gemm_legacy3(
    const u16* __restrict__ A, const float* __restrict__ B0,
    const float* __restrict__ bias, float* __restrict__ of,
    int M, int N, int K) {
  __shared__ u16 Al[128 * 32];
  __shared__ u16 Bl[32 * 128];
  const int tid = threadIdx.x;
  const int lane = tid & 63;
  const int wid = tid >> 6;
  const int bn = blockIdx.x;
  const int bm = blockIdx.y;
  const int wr = wid >> 1, wc = wid & 1;
  const int l15 = lane & 15, lg = lane >> 4;
  f32x4 acc[4][4];
  #pragma unroll
  for (int i = 0; i < 4; ++i)
    #pragma unroll
    for (int j = 0; j < 4; ++j) { f32x4 z = {0.f,0.f,0.f,0.f}; acc[i][j] = z; }
  const u16* Abase = A + (size_t)(bm * 128) * K;
  const int ar0 = tid >> 2;
  const int ac0 = (tid & 3) * 8;
  const int brow = tid >> 3;
  const int bc0 = (tid & 7) * 16;
  for (int kt = 0; kt < K; kt += 32) {
    *(u16x8*)(Al + ar0 * 32 + ac0) =
        *(const u16x8*)(Abase + (size_t)ar0 * K + kt + ac0);
    *(u16x8*)(Al + (ar0 + 64) * 32 + ac0) =
        *(const u16x8*)(Abase + (size_t)(ar0 + 64) * K + kt + ac0);
    {
      const float* bsrc = B0 + (size_t)(kt + brow) * N + bn * 128 + bc0;
      alignas(16) u16 tmp[16];
      const int colbase = bn * 128 + bc0;
      #pragma unroll
      for (int q = 0; q < 16; ++q)
        tmp[q] = f2bf((colbase + q < N) ? bsrc[q] : 0.0f);
      *(u16x8*)(Bl + brow * 128 + bc0) = *(const u16x8*)tmp;
      *(u16x8*)(Bl + brow * 128 + bc0 + 8) = *(const u16x8*)(tmp + 8);
    }
    __syncthreads();
    bf16x8 af[4];
    #pragma unroll
    for (int mi = 0; mi < 4; ++mi)
      af[mi] = *(const bf16x8*)(Al + (wr * 64 + mi * 16 + l15) * 32 + lg * 8);
    #pragma unroll
    for (int ni = 0; ni < 4; ++ni) {
      u16x8 tv;
      #pragma unroll
      for (int i = 0; i < 8; ++i)
        tv[i] = Bl[(lg * 8 + i) * 128 + wc * 64 + ni * 16 + l15];
      const bf16x8 bfr = __builtin_bit_cast(bf16x8, tv);
      #pragma unroll
      for (int mi = 0; mi < 4; ++mi)
        acc[mi][ni] = __builtin_amdgcn_mfma_f32_16x16x32_bf16(af[mi], bfr, acc[mi][ni], 0, 0, 0);
    }
    __syncthreads();
  }
  #pragma unroll
  for (int mi = 0; mi < 4; ++mi) {
    const int grow = bm * 128 + wr * 64 + mi * 16 + lg * 4;
    #pragma unroll
    for (int ni = 0; ni < 4; ++ni) {
      const int gcol = bn * 128 + wc * 64 + ni * 16 + l15;
      #pragma unroll
      for (int r = 0; r < 4; ++r)
        if (gcol < N) of[(size_t)(grow + r) * N + gcol] = acc[mi][ni][r] + bias[gcol];
    }
  }
}

// ------ causal flash attention: 4 q-tiles (256 rows) per block, 8 waves ------
// grid (T/256, B*H), 512 thr. Wave w owns TWO 16-row q-groups g=0,1 at
// qwr_g = bx*256 + g*128 + w*16 (all state duplicated per group). K/V staged
// ONCE per kv-tile for all 256 q-rows. Causal skip wave-uniform per group.
__global__ __launch_bounds__(512, 2) void k_attn(
    const u16* __restrict__ qg, const u16* __restrict__ kg,
    const u16* __restrict__ vg, u16* __restrict__ og) {
  __shared__ u16 Kl[64 * 64];
  __shared__ u16 Vt[64 * 64];
  __shared__ u16 Pl[8][2][16 * 64];   // 32 KB
  const int tid = threadIdx.x;
  const int lane = tid & 63;
  const int w = tid >> 6;            // 0..7
  const int bx = blockIdx.x;         // 0..T/256-1
  const int bh = blockIdx.y;
  const int b = bh >> 4, h = bh & 15;
  const int l15 = lane & 15, lg = lane >> 4;
  char* KlB = (char*)Kl;
  char* VtB = (char*)Vt;

  int qwr[2], diagkt[2];
  size_t qrow0[2];
  bf16x8 aq[2][2];
  #pragma unroll
  for (int g = 0; g < 2; ++g) {
    qwr[g] = bx * 256 + g * 128 + w * 16;
    diagkt[g] = qwr[g] >> 6;
    qrow0[g] = (size_t)b * cT + qwr[g];
    #pragma unroll
    for (int c = 0; c < 2; ++c)
      aq[g][c] = *(const bf16x8*)(qg + (qrow0[g] + l15) * cE + h * 64 + c * 32 + lg * 8);
  }

  f32x4 acco[2][4];
  float mrun[2][4], lrun[2][4];
  #pragma unroll
  for (int g = 0; g < 2; ++g) {
    #pragma unroll
    for (int j = 0; j < 4; ++j) { f32x4 z = {0.f,0.f,0.f,0.f}; acco[g][j] = z; }
    #pragma unroll
    for (int r = 0; r < 4; ++r) { mrun[g][r] = -1e30f; lrun[g][r] = 0.f; }
  }

  const int ktmax = 4 * bx + 3;
  for (int kt = 0; kt <= ktmax; ++kt) {
    const size_t krow0 = (size_t)b * cT + kt * 64;
    {
      const int rr = tid >> 3, c8 = (tid & 7) * 8;   // 512 thr cover 64x64
      *(u16x8*)(KlB + rr * 128 + swzoff(rr, c8 >> 3)) =
          *(const u16x8*)(kg + (krow0 + rr) * cE + h * 64 + c8);
      const u16x8 vv = *(const u16x8*)(vg + (krow0 + rr) * cE + h * 64 + c8);
      #pragma unroll
      for (int i = 0; i < 8; ++i)
        *(u16*)(VtB + (c8 + i) * 128 + swzoff(c8 + i, rr >> 3) + (rr & 7) * 2) = vv[i];
    }
    __syncthreads();

    #pragma unroll
    for (int g = 0; g < 2; ++g) {
      if (kt <= diagkt[g]) {                 // wave-uniform causal skip
        char* PlB = (char*)(Pl[w][g]);
        f32x4 s[4];
        #pragma unroll
        for (int j = 0; j < 4; ++j) { f32x4 z = {0.f,0.f,0.f,0.f}; s[j] = z; }
        #pragma unroll
        for (int c = 0; c < 2; ++c) {
          #pragma unroll
          for (int j = 0; j < 4; ++j) {
            const int n = j * 16 + l15;
            const bf16x8 kb2 = *(const bf16x8*)(KlB + n * 128 + swzoff(n, c * 4 + lg));
            s[j] = __builtin_amdgcn_mfma_f32_16x16x32_bf16(aq[g][c], kb2, s[j], 0, 0, 0);
          }
        }

        float sv[4][4];
        const bool diag = (kt == diagkt[g]);
        #pragma unroll
        for (int j = 0; j < 4; ++j)
          #pragma unroll
          for (int r = 0; r < 4; ++r) {
            float xs = s[j][r] * 0.125f;
            if (diag && (kt * 64 + j * 16 + l15) > (qwr[g] + lg * 4 + r)) xs = -1e30f;
            sv[j][r] = xs;
          }

        float corr[4];
        #pragma unroll
        for (int r = 0; r < 4; ++r) {
          float mx = fmaxf(fmaxf(sv[0][r], sv[1][r]), fmaxf(sv[2][r], sv[3][r]));
          #pragma unroll
          for (int off = 1; off < 16; off <<= 1) mx = fmaxf(mx, __shfl_xor(mx, off));
          const float mnew = fmaxf(mrun[g][r], mx);
          corr[r] = __expf(mrun[g][r] - mnew);
          float rs = 0.f;
          #pragma unroll
          for (int j = 0; j < 4; ++j) {
            const float p = __expf(sv[j][r] - mnew);
            sv[j][r] = p;
            rs += p;
          }
          #pragma unroll
          for (int off = 1; off < 16; off <<= 1) rs += __shfl_xor(rs, off);
          lrun[g][r] = lrun[g][r] * corr[r] + rs;
          mrun[g][r] = mnew;
        }

        #pragma unroll
        for (int j = 0; j < 4; ++j)
          #pragma unroll
          for (int r = 0; r < 4; ++r) {
            const int qr = lg * 4 + r, kc = j * 16 + l15;
            *(u16*)(PlB + qr * 128 + swzoff(qr, kc >> 3) + (kc & 7) * 2) = f2bf(sv[j][r]);
            acco[g][j][r] *= corr[r];
          }

        #pragma unroll
        for (int c = 0; c < 2; ++c) {
          const bf16x8 pa = *(const bf16x8*)(PlB + l15 * 128 + swzoff(l15, c * 4 + lg));
          #pragma unroll
          for (int j = 0; j < 4; ++j) {
            const int n = j * 16 + l15;
            const bf16x8 vb2 = *(const bf16x8*)(VtB + n * 128 + swzoff(n, c * 4 + lg));
            acco[g][j] = __builtin_amdgcn_mfma_f32_16x16x32_bf16(pa, vb2, acco[g][j], 0, 0, 0);
          }
        }
      }
    }
    __syncthreads();
  }

  #pragma unroll
  for (int g = 0; g < 2; ++g)
    #pragma unroll
    for (int j = 0; j < 4; ++j)
      #pragma unroll
      for (int r = 0; r < 4; ++r)
        og[(qrow0[g] + lg * 4 + r) * cE + h * 64 + j * 16 + l15] =
            f2bf(acco[g][j][r] / lrun[g][r]);
}

// ---------------- NLL from per-tile partials ----------------
__global__ __launch_bounds__(256) void k_nll2(const float* __restrict__ pm,
    const float* __restrict__ ps, const float* __restrict__ logits,
    const int* __restrict__ tgt, float* __restrict__ nll, int NT) {
  const int row = blockIdx.x * 4 + (threadIdx.x >> 6);
  const int lane = threadIdx.x & 63;
  float m = -1e30f, s = 0.f;
  for (int i = lane; i < NT; i += 64) {
    const float m2 = pm[(size_t)row * NT + i];
    const float s2 = ps[(size_t)row * NT + i];
    const float M = fmaxf(m, m2);
    s = s * __expf(m - M) + s2 * __expf(m2 - M);
    m = M;
  }
  #pragma unroll
  for (int off = 1; off < 64; off <<= 1) {
    const float m2 = __shfl_xor(m, off);
    const float s2 = __shfl_xor(s, off);
    const float M = fmaxf(m, m2);
    s = s * __expf(m - M) + s2 * __expf(m2 - M);
    m = M;
  }
  if (lane == 0)
    nll[row] = logf(s) + m - logits[(size_t)row * cV + tgt[row]];
}

// ---------------- per-row NLL over V (fallback) ----------------
__global__ __launch_bounds__(256) void k_nll(const float* __restrict__ logits,
    const int* __restrict__ tgt, float* __restrict__ nll) {
  const int row = blockIdx.x;
  const float* lp = logits + (size_t)row * cV;
  const int t = threadIdx.x;
  __shared__ float red[8];
  const int wid = t >> 6, lane = t & 63;
  float mx = -1e30f;
  for (int i = t; i < cV; i += 256) mx = fmaxf(mx, lp[i]);
  #pragma unroll
  for (int off = 32; off; off >>= 1) mx = fmaxf(mx, __shfl_xor(mx, off));
  if (lane == 0) red[wid] = mx;
  __syncthreads();
  mx = fmaxf(fmaxf(red[0], red[1]), fmaxf(red[2], red[3]));
  float s = 0.f;
  for (int i = t; i < cV; i += 256) s += __expf(lp[i] - mx);
  #pragma unroll
  for (int off = 32; off; off >>= 1) s += __shfl_xor(s, off);
  if (lane == 0) red[4 + wid] = s;
  __syncthreads();
  if (t == 0) {
    s = red[4] + red[5] + red[6] + red[7];
    nll[row] = logf(s) + mx - lp[tgt[row]];
  }
}

__global__ __launch_bounds__(256) void k_loss(const float* __restrict__ nll,
    float* __restrict__ out) {
  const int t = threadIdx.x;
  float s = 0.f;
  for (int i = t; i < cBT; i += 256) s += nll[i];
  #pragma unroll
  for (int off = 32; off; off >>= 1) s += __shfl_xor(s, off);
  __shared__ float red[4];
  if ((t & 63) == 0) red[t >> 6] = s;
  __syncthreads();
  if (t == 0) out[0] = (red[0] + red[1] + red[2] + red[3]) * (1.0f / cBT);
}

extern "C" void kernel_launch(void* const* d_in, const int* in_sizes, int n_in,
                              void* d_out, int out_size, void* d_ws, size_t ws_size,
                              hipStream_t stream) {
  const int*   idx  = (const int*)d_in[0];
  const int*   tgt  = (const int*)d_in[1];
  const float* tok  = (const float*)d_in[2];
  const float* pos  = (const float*)d_in[3];
  const float* Wq   = (const float*)d_in[4];
  const float* Wk   = (const float*)d_in[5];
  const float* Wv   = (const float*)d_in[6];
  const float* Wo   = (const float*)d_in[7];
  const float* bo   = (const float*)d_in[8];
  const float* ln1g = (const float*)d_in[9];
  const float* ln1b = (const float*)d_in[10];
  const float* ln2g = (const float*)d_in[11];
  const float* ln2b = (const float*)d_in[12];
  const float* W1   = (const float*)d_in[13];
  const float* b1   = (const float*)d_in[14];
  const float* W2   = (const float*)d_in[15];
  const float* b2   = (const float*)d_in[16];
  const float* lnfg = (const float*)d_in[17];
  const float* lnfb = (const float*)d_in[18];
  const float* Wh   = (const float*)d_in[19];
  const float* bh   = (const float*)d_in[20];

  // --- d_out scratch plan (all dead before head GEMM overwrites d_out) ---
  char* ob = (char*)d_out;
  u16* x      = (u16*)ob;                            // [BT,E] bf16, 8 MB
  u16* hb     = (u16*)(ob + (16u << 20));
  u16* qb     = (u16*)(ob + (24u << 20));            // q/k/v contiguous slabs
  u16* kb     = (u16*)(ob + (32u << 20));
  u16* vb     = (u16*)(ob + (40u << 20));
  u16* abuf   = (u16*)(ob + (48u << 20));
  u16* fbuf   = (u16*)(ob + (56u << 20));            // [BT,FF] bf16 -> ends 88M
  u16* W3T    = (u16*)(ob + (128u << 20));           // 12 x [3][E][E] (72MB) -> 200M
  u16* WoT    = (u16*)(ob + (200u << 20));           // 12 x [E][E]   (24MB) -> 224M
  u16* W1T    = (u16*)(ob + (224u << 20));           // 12 x [FF][E]  (96MB) -> 320M
  u16* W2T    = (u16*)(ob + (320u << 20));           // 12 x [E][FF]  (96MB) -> 416M
  // --- d_ws layout ---
  u16* hf     = (u16*)d_ws;                          // 8.39 MB
  float* nll  = (float*)((char*)d_ws + 8388608);
  u16* WheadT = (u16*)((char*)d_ws + 8404992);       // [cVp][E] bf16 (103.3 MB)
  const size_t whead_end = 8404992u + (size_t)cVp * cE * 2u;
  float* pmax = (float*)((char*)d_ws + whead_end);
  float* psum = (float*)((char*)d_ws + whead_end + (size_t)cBT * cNT * 4);
  const size_t ws_need = whead_end + 2u * (size_t)cBT * cNT * 4;
  const bool fast_head = ws_size >= ws_need;

  float* logits = (float*)d_out;
  float* loss = logits + (size_t)cBT * cV;

  const dim3 blk(256);
  const size_t e2 = (size_t)cE * cE, ef = (size_t)cE * cFF;

  // weight conversion (every call)
  k_cvt_t<<<dim3(16, 32, cL), blk, 0, stream>>>(Wq, W3T,          cE, cE, e2, 3 * e2);
  k_cvt_t<<<dim3(16, 32, cL), blk, 0, stream>>>(Wk, W3T + e2,     cE, cE, e2, 3 * e2);
  k_cvt_t<<<dim3(16, 32, cL), blk, 0, stream>>>(Wv, W3T + 2 * e2, cE, cE, e2, 3 * e2);
  k_cvt_t<<<dim3(16, 32, cL), blk, 0, stream>>>(Wo, WoT, cE, cE, e2, e2);
  k_cvt_t<<<dim3(64, 32, cL), blk, 0, stream>>>(W1, W1T, cE, cFF, ef, ef);
  k_cvt_t<<<dim3(16, 128, cL), blk, 0, stream>>>(W2, W2T, cFF, cE, ef, ef);
  if (fast_head)
    k_cvt_t<<<dim3(cVp / 64, 32, 1), blk, 0, stream>>>(Wh, WheadT, cE, cV, 0, 0);

  k_embed<<<dim3(cBT), blk, 0, stream>>>(idx, tok, pos, x);
  for (int l = 0; l < cL; ++l) {
    k_ln<<<dim3(cBT), blk, 0, stream>>>(x, ln1g + l * cE, ln1b + l * cE, hb);
    k_gemm2<0><<<dim3(32 * 12), dim3(512), 0, stream>>>(hb, W3T + l * 3 * e2,
        nullptr, qb, nullptr, cE, 3072, 0, 32, nullptr, nullptr);
    k_attn<<<dim3(4, 64), dim3(512), 0, stream>>>(qb, kb, vb, abuf);
    k_gemm_s<<<dim3(512), blk, 0, stream>>>(abuf, WoT + l * e2, bo + l * cE, x, cE, cE, 64);
    k_ln<<<dim3(cBT), blk, 0, stream>>>(x, ln2g + l * cE, ln2b + l * cE, hb);
    k_gemm2<2><<<dim3(32 * 16), dim3(512), 0, stream>>>(hb, W1T + l * ef,
        b1 + l * cFF, fbuf, nullptr, cE, cFF, 0, 32, nullptr, nullptr);
    k_gemm_s<<<dim3(512), blk, 0, stream>>>(fbuf, W2T + l * ef, b2 + l * cE, x, cFF, cE, 64);
  }
  k_ln<<<dim3(cBT), blk, 0, stream>>>(x, lnfg, lnfb, hf);
  if (fast_head) {
    k_gemm2<3><<<dim3(32 * cNT), dim3(512), 0, stream>>>(hf, WheadT, bh,
        nullptr, logits, cE, cV, cNT, 32, pmax, psum);
    k_nll2<<<dim3(cBT / 4), blk, 0, stream>>>(pmax, psum, logits, tgt, nll, cNT);
  } else {
    k_gemm_legacy3<<<dim3(393, 32), blk, 0, stream>>>(hf, Wh, bh, logits, cBT, cV, cE);
    k_nll<<<dim3(cBT), blk, 0, stream>>>(logits, tgt, nll);
  }
  k_loss<<<dim3(1), blk, 0, stream>>>(nll, loss);
}

// Round 16
// 3865.899 us; speedup vs baseline: 1.1260x; 1.0028x over previous
//
#include <hip/hip_runtime.h>
#include <cstdint>
#include <cstddef>

typedef unsigned short u16;
typedef __bf16 bf16x8 __attribute__((ext_vector_type(8)));
typedef float f32x4 __attribute__((ext_vector_type(4)));
typedef unsigned short u16x8 __attribute__((ext_vector_type(8)));
typedef unsigned short u16x4 __attribute__((ext_vector_type(4)));

constexpr int cV  = 50257;
constexpr int cVp = 50432;      // padded to 256
constexpr int cNT = cVp / 256;  // 197 head n-tiles
constexpr int cT  = 1024;
constexpr int cE  = 1024;
constexpr int cL  = 12;
constexpr int cFF = 4096;
constexpr int cBT = 4096;       // B*T

__device__ __forceinline__ u16 f2bf(float f) {
  union { float f; unsigned u; } x; x.f = f;
  unsigned r = x.u + 0x7fffu + ((x.u >> 16) & 1u);   // RNE
  return (u16)(r >> 16);
}
__device__ __forceinline__ float bf2f(u16 h) {
  union { unsigned u; float f; } z; z.u = ((unsigned)h) << 16; return z.f;
}

// async global->LDS, 16B per lane. dest must be linear in lane order.
__device__ __forceinline__ void gload16(const void* g, void* l) {
  __builtin_amdgcn_global_load_lds(
      (const __attribute__((address_space(1))) void*)g,
      (__attribute__((address_space(3))) void*)l, 16, 0, 0);
}

// XOR swizzle for 128B-wide LDS rows (attn): permute 16B chunks within row.
__device__ __forceinline__ int swzoff(int row, int chunk) {
  return ((chunk ^ (row & 7) ^ ((row >> 3) & 7)) << 4);
}

// bijective XCD-chunk swizzle for grids with nwg % 8 == 0 (k_gemm_s only)
__device__ __forceinline__ int xcd_swz(int id, int nwg) {
  if ((nwg & 7) == 0) { const int q = nwg >> 3; return (id & 7) * q + (id >> 3); }
  return id;
}

// ---------------- embedding: x(bf16) = tok_emb[idx] + pos_emb ----------------
__global__ __launch_bounds__(256) void k_embed(const int* __restrict__ idx,
    const float* __restrict__ tok, const float* __restrict__ pos,
    u16* __restrict__ x) {
  const int row = blockIdx.x;
  const int t = row & (cT - 1);
  const int tk = idx[row];
  const float4* tv = (const float4*)(tok + (size_t)tk * cE);
  const float4* pv = (const float4*)(pos + (size_t)t * cE);
  const int i = threadIdx.x;
  float4 a = tv[i];
  float4 p = pv[i];
  u16x4 o;
  o[0] = f2bf(a.x + p.x); o[1] = f2bf(a.y + p.y);
  o[2] = f2bf(a.z + p.z); o[3] = f2bf(a.w + p.w);
  ((u16x4*)(x + (size_t)row * cE))[i] = o;
}

// ------- layernorm v2: one ROW per WAVE (bf16 in -> bf16 out) -------
// 4 rows/block, 16 elems/lane as two coalesced u16x8 halves; wave-local
// shfl reduction only (no LDS, no barrier).
__global__ __launch_bounds__(256) void k_ln(const u16* __restrict__ x,
    const float* __restrict__ gw, const float* __restrict__ bw,
    u16* __restrict__ out) {
  const int row = blockIdx.x * 4 + (threadIdx.x >> 6);
  const int lane = threadIdx.x & 63;
  const u16* xr = x + (size_t)row * cE;
  const u16x8 va = ((const u16x8*)xr)[lane];          // elems [lane*8, +8)
  const u16x8 vb = ((const u16x8*)(xr + 512))[lane];  // elems [512+lane*8, +8)
  float f[16];
  #pragma unroll
  for (int i = 0; i < 8; ++i) { f[i] = bf2f(va[i]); f[8 + i] = bf2f(vb[i]); }
  float s1 = 0.f, s2 = 0.f;
  #pragma unroll
  for (int i = 0; i < 16; ++i) { s1 += f[i]; s2 += f[i] * f[i]; }
  #pragma unroll
  for (int off = 32; off; off >>= 1) {
    s1 += __shfl_xor(s1, off);
    s2 += __shfl_xor(s2, off);
  }
  const float mean = s1 * (1.0f / cE);
  const float var = s2 * (1.0f / cE) - mean * mean;
  const float rs = rsqrtf(var + 1e-5f);
  const float4* g4a = (const float4*)(gw + lane * 8);
  const float4* b4a = (const float4*)(bw + lane * 8);
  const float4* g4b = (const float4*)(gw + 512 + lane * 8);
  const float4* b4b = (const float4*)(bw + 512 + lane * 8);
  float g[16], bb[16];
  { float4 t0 = g4a[0], t1 = g4a[1];
    g[0]=t0.x; g[1]=t0.y; g[2]=t0.z; g[3]=t0.w; g[4]=t1.x; g[5]=t1.y; g[6]=t1.z; g[7]=t1.w; }
  { float4 t0 = g4b[0], t1 = g4b[1];
    g[8]=t0.x; g[9]=t0.y; g[10]=t0.z; g[11]=t0.w; g[12]=t1.x; g[13]=t1.y; g[14]=t1.z; g[15]=t1.w; }
  { float4 t0 = b4a[0], t1 = b4a[1];
    bb[0]=t0.x; bb[1]=t0.y; bb[2]=t0.z; bb[3]=t0.w; bb[4]=t1.x; bb[5]=t1.y; bb[6]=t1.z; bb[7]=t1.w; }
  { float4 t0 = b4b[0], t1 = b4b[1];
    bb[8]=t0.x; bb[9]=t0.y; bb[10]=t0.z; bb[11]=t0.w; bb[12]=t1.x; bb[13]=t1.y; bb[14]=t1.z; bb[15]=t1.w; }
  u16x8 oa, ob;
  #pragma unroll
  for (int i = 0; i < 8; ++i) {
    oa[i] = f2bf((f[i] - mean) * rs * g[i] + bb[i]);
    ob[i] = f2bf((f[8 + i] - mean) * rs * g[8 + i] + bb[8 + i]);
  }
  u16* orow = out + (size_t)row * cE;
  ((u16x8*)orow)[lane] = oa;
  ((u16x8*)(orow + 512))[lane] = ob;
}

// ------- weight convert+transpose: f32[K][N] -> bf16[N][K], vectorized -------
__global__ __launch_bounds__(256) void k_cvt_t(const float* __restrict__ src,
    u16* __restrict__ dst, int K, int Nsrc, size_t sstride, size_t dstride) {
  __shared__ float tile[32][65];
  const float* s = src + blockIdx.z * sstride;
  u16* d = dst + blockIdx.z * dstride;
  const int n0 = blockIdx.x * 64, k0 = blockIdx.y * 32;
  const int t = threadIdx.x;
  #pragma unroll
  for (int p = 0; p < 2; ++p) {
    const int li = p * 256 + t;
    const int k = li >> 4;            // 0..31
    const int n4 = (li & 15) * 4;     // 0..60
    const float* sp = s + (size_t)(k0 + k) * Nsrc + n0 + n4;
    if ((n0 + n4 + 3 < Nsrc) && ((((size_t)(k0 + k) * Nsrc + n0 + n4) & 3) == 0)) {
      const float4 f = *(const float4*)sp;
      tile[k][n4] = f.x; tile[k][n4 + 1] = f.y;
      tile[k][n4 + 2] = f.z; tile[k][n4 + 3] = f.w;
    } else {
      #pragma unroll
      for (int i = 0; i < 4; ++i)
        tile[k][n4 + i] = (n0 + n4 + i < Nsrc) ? sp[i] : 0.0f;
    }
  }
  __syncthreads();
  #pragma unroll
  for (int p = 0; p < 2; ++p) {
    const int si = p * 256 + t;
    const int n = si >> 3;            // 0..63
    const int k4 = (si & 7) * 4;      // 0..28
    u16x4 o;
    #pragma unroll
    for (int i = 0; i < 4; ++i) o[i] = f2bf(tile[k4 + i][n]);
    *(u16x4*)(d + (size_t)(n0 + n) * K + k0 + k4) = o;
  }
}

// ============== 128x256 GEMM, BK=32, 2 blocks/CU (round-11 best) ==============
// GEMM plateau established (rounds 6-13): ~650 TF across 5 schedule/tile
// variants at K=1024 (LDS-BW bound); this is the simplest best one.
// (512,4): no spill (round-9 lesson). Plain stores (round-8 NT lesson).
// No pinning (m141). One __syncthreads per K-tile; stage(t+1) issued first.
template<int EPI>
__global__ __launch_bounds__(512, 4) void k_gemm2(
    const u16* __restrict__ A, const u16* __restrict__ Bt,
    const float* __restrict__ bias, u16* __restrict__ obf,
    float* __restrict__ of, int K, int Nout, int ntile, int mt,
    float* __restrict__ pm, float* __restrict__ ps) {
  __shared__ __align__(16) char smem[49152];
  const int tid = threadIdx.x;
  const int lane = tid & 63;
  const int wid = tid >> 6;
  const int wg = (int)blockIdx.x;
  const int bm = wg % mt;            // bm-fast: all CUs sweep same B panel
  const int bn = wg / mt;
  const int wm = wid >> 2, wn = wid & 3;
  const int l15 = lane & 15, lg = lane >> 4;

  f32x4 acc[4][4];
  #pragma unroll
  for (int i = 0; i < 4; ++i)
    #pragma unroll
    for (int j = 0; j < 4; ++j) { f32x4 z = {0.f,0.f,0.f,0.f}; acc[i][j] = z; }

  const u16* Ab = A + (size_t)(bm * 128) * K;
  const u16* Bb = Bt + (size_t)(bn * 256) * K;
  const int nt = K >> 5;

  auto stage = [&](int t) {
    char* buf = smem + ((t & 1) ? 24576 : 0);
    const int kt = t << 5;
    {
      const int r = tid >> 2, c = tid & 3;
      gload16(Ab + (size_t)r * K + kt + ((c ^ ((r >> 1) & 3)) << 3),
              buf + tid * 16);
    }
    #pragma unroll
    for (int p = 0; p < 2; ++p) {
      const int L = p * 512 + tid;
      const int r = L >> 2, c = L & 3;
      gload16(Bb + (size_t)r * K + kt + ((c ^ ((r >> 1) & 3)) << 3),
              buf + 8192 + L * 16);
    }
  };

  stage(0);
  for (int t = 0; t < nt; ++t) {
    __syncthreads();                     // tile t landed; readers of t-1 done
    if (t + 1 < nt) stage(t + 1);        // overlap loads with compute(t)
    char* cs = smem + ((t & 1) ? 24576 : 0);
    const char* csB = cs + 8192;
    bf16x8 af[4], bfr[4];
    #pragma unroll
    for (int mi = 0; mi < 4; ++mi) {
      const int row = wm * 64 + mi * 16 + l15;
      af[mi] = *(const bf16x8*)(cs + row * 64 + ((lg ^ ((row >> 1) & 3)) << 4));
    }
    #pragma unroll
    for (int ni = 0; ni < 4; ++ni) {
      const int row = wn * 64 + ni * 16 + l15;
      bfr[ni] = *(const bf16x8*)(csB + row * 64 + ((lg ^ ((row >> 1) & 3)) << 4));
    }
    #pragma unroll
    for (int ni = 0; ni < 4; ++ni)
      #pragma unroll
      for (int mi = 0; mi < 4; ++mi)
        acc[mi][ni] = __builtin_amdgcn_mfma_f32_16x16x32_bf16(af[mi], bfr[ni], acc[mi][ni], 0, 0, 0);
  }

  // ---- epilogue ----
  if constexpr (EPI == 3) {
    __syncthreads();                      // repurpose smem
    float* pb = (float*)smem;             // [128][4][2]
    #pragma unroll
    for (int mi = 0; mi < 4; ++mi) {
      const int grow = bm * 128 + wm * 64 + mi * 16 + lg * 4;
      float rm[4];
      #pragma unroll
      for (int r = 0; r < 4; ++r) rm[r] = -1e30f;
      #pragma unroll
      for (int ni = 0; ni < 4; ++ni) {
        const int gcol = bn * 256 + wn * 64 + ni * 16 + l15;
        const bool ok = gcol < Nout;
        const float bb = ok ? bias[gcol] : 0.0f;
        #pragma unroll
        for (int r = 0; r < 4; ++r) {
          const float v = ok ? (acc[mi][ni][r] + bb) : -1e30f;
          acc[mi][ni][r] = v;
          if (ok) of[(size_t)(grow + r) * Nout + gcol] = v;
          rm[r] = fmaxf(rm[r], v);
        }
      }
      #pragma unroll
      for (int r = 0; r < 4; ++r) {
        float m = rm[r];
        #pragma unroll
        for (int off = 1; off < 16; off <<= 1) m = fmaxf(m, __shfl_xor(m, off));
        float s = 0.f;
        #pragma unroll
        for (int ni = 0; ni < 4; ++ni) s += __expf(acc[mi][ni][r] - m);
        #pragma unroll
        for (int off = 1; off < 16; off <<= 1) s += __shfl_xor(s, off);
        if (l15 == 0) {
          const int lrow = wm * 64 + mi * 16 + lg * 4 + r;
          pb[(lrow * 4 + wn) * 2] = m;
          pb[(lrow * 4 + wn) * 2 + 1] = s;
        }
      }
    }
    __syncthreads();
    if (tid < 128) {
      float m = -1e30f, s = 0.f;
      #pragma unroll
      for (int q = 0; q < 4; ++q) {
        const float m2 = pb[(tid * 4 + q) * 2];
        const float s2 = pb[(tid * 4 + q) * 2 + 1];
        const float M = fmaxf(m, m2);
        s = s * __expf(m - M) + s2 * __expf(m2 - M);
        m = M;
      }
      const size_t grow = (size_t)(bm * 128 + tid);
      pm[grow * ntile + bn] = m;
      ps[grow * ntile + bn] = s;
    }
  } else {
    #pragma unroll
    for (int mi = 0; mi < 4; ++mi) {
      const int grow = bm * 128 + wm * 64 + mi * 16 + lg * 4;
      #pragma unroll
      for (int ni = 0; ni < 4; ++ni) {
        const int gcol = bn * 256 + wn * 64 + ni * 16 + l15;
        #pragma unroll
        for (int r = 0; r < 4; ++r) {
          const float a = acc[mi][ni][r];
          if constexpr (EPI == 0) {
            obf[(size_t)(gcol >> 10) * 4194304 + (size_t)(grow + r) * 1024 + (gcol & 1023)] = f2bf(a);
          } else {
            const float gv = a + bias[gcol];
            obf[(size_t)(grow + r) * Nout + gcol] = f2bf(0.5f * gv * (1.0f + erff(gv * 0.70710678118f)));
          }
        }
      }
    }
  }
}

// ------- small-M pipelined GEMM: 64x128 tile, BK=64, residual += (bf16 x) -------
__global__ __launch_bounds__(256) void k_gemm_s(
    const u16* __restrict__ A, const u16* __restrict__ Bt,
    const float* __restrict__ bias, u16* __restrict__ of,
    int K, int Nout, int mt) {
  __shared__ __align__(16) char smem[49152];
  const int tid = threadIdx.x;
  const int lane = tid & 63;
  const int wid = tid >> 6;
  const int wg = xcd_swz((int)blockIdx.x, (int)gridDim.x);
  const int bm = wg % mt;
  const int bn = wg / mt;
  const int wr = wid >> 1, wc = wid & 1;
  const int l15 = lane & 15, lg = lane >> 4;

  f32x4 acc[2][4];
  #pragma unroll
  for (int i = 0; i < 2; ++i)
    #pragma unroll
    for (int j = 0; j < 4; ++j) { f32x4 z = {0.f,0.f,0.f,0.f}; acc[i][j] = z; }

  const u16* Ab = A + (size_t)(bm * 64) * K;
  const u16* Bb = Bt + (size_t)(bn * 128) * K;
  const int nt = K >> 6;

  auto stage = [&](int t, char* buf) {
    const int kt = (t < nt ? t : nt - 1) << 6;
    #pragma unroll
    for (int p = 0; p < 2; ++p) {
      const int L = p * 256 + tid;
      const int row = L >> 3, cc = L & 7;
      gload16(Ab + (size_t)row * K + kt + ((cc ^ (row & 7)) << 3), buf + L * 16);
    }
    #pragma unroll
    for (int p = 0; p < 4; ++p) {
      const int L = p * 256 + tid;
      const int row = L >> 3, cc = L & 7;
      gload16(Bb + (size_t)row * K + kt + ((cc ^ (row & 7)) << 3), buf + 8192 + L * 16);
    }
  };
  stage(0, smem);
  stage(1, smem + 24576);

  for (int t = 0; t < nt; ++t) {
    char* cs = smem + ((t & 1) ? 24576 : 0);
    const char* csB = cs + 8192;
    asm volatile("s_waitcnt vmcnt(6)" ::: "memory");
    __builtin_amdgcn_s_barrier();

    bf16x8 af[2][2], bfr[4][2];
    #pragma unroll
    for (int mi = 0; mi < 2; ++mi) {
      const int row = wr * 32 + mi * 16 + l15;
      #pragma unroll
      for (int kk = 0; kk < 2; ++kk)
        af[mi][kk] = *(const bf16x8*)(cs + row * 128 + (((kk * 4 + lg) ^ (row & 7)) << 4));
    }
    #pragma unroll
    for (int ni = 0; ni < 4; ++ni) {
      const int row = wc * 64 + ni * 16 + l15;
      #pragma unroll
      for (int kk = 0; kk < 2; ++kk)
        bfr[ni][kk] = *(const bf16x8*)(csB + row * 128 + (((kk * 4 + lg) ^ (row & 7)) << 4));
    }
    __builtin_amdgcn_sched_barrier(0);
    __builtin_amdgcn_s_setprio(1);
    #pragma unroll
    for (int ni = 0; ni < 4; ++ni)
      #pragma unroll
      for (int mi = 0; mi < 2; ++mi)
        acc[mi][ni] = __builtin_amdgcn_mfma_f32_16x16x32_bf16(af[mi][0], bfr[ni][0], acc[mi][ni], 0, 0, 0);
    __builtin_amdgcn_s_setprio(0);
    __builtin_amdgcn_sched_barrier(0);
    asm volatile("s_waitcnt lgkmcnt(0)" ::: "memory");
    __builtin_amdgcn_sched_barrier(0);
    __builtin_amdgcn_s_barrier();

    stage(t + 2, cs);
    __builtin_amdgcn_sched_barrier(0);
    __builtin_amdgcn_s_setprio(1);
    #pragma unroll
    for (int ni = 0; ni < 4; ++ni)
      #pragma unroll
      for (int mi = 0; mi < 2; ++mi)
        acc[mi][ni] = __builtin_amdgcn_mfma_f32_16x16x32_bf16(af[mi][1], bfr[ni][1], acc[mi][ni], 0, 0, 0);
    __builtin_amdgcn_s_setprio(0);
    __builtin_amdgcn_sched_barrier(0);
  }
  asm volatile("s_waitcnt vmcnt(0)" ::: "memory");

  #pragma unroll
  for (int mi = 0; mi < 2; ++mi) {
    const int grow = bm * 64 + wr * 32 + mi * 16 + lg * 4;
    #pragma unroll
    for (int ni = 0; ni < 4; ++ni) {
      const int gcol = bn * 128 + wc * 64 + ni * 16 + l15;
      #pragma unroll
      for (int r = 0; r < 4; ++r) {
        u16* xp = of + (size_t)(grow + r) * Nout + gcol;
        *xp = f2bf(bf2f(*xp) + acc[mi][ni][r] + bias[gcol]);
      }
    }
  }
}

// ---------------- legacy head GEMM (f32 B, used only if d_ws too small) ----------------
__global__ __launch_bounds__(256) void k_gemm_legacy3(
    const u16* __restrict__ A, const float* __restrict__ B0,
    const float* __restrict__ bias, float* __restrict__ of,
    int M, int N, int K) {
  __shared__ u16 Al[128 * 32];
  __shared__ u16 Bl[32 * 128];
  const int tid = threadIdx.x;
  const int lane = tid & 63;
  const int wid = tid >> 6;
  const int bn = blockIdx.x;
  const int bm = blockIdx.y;
  const int wr = wid >> 1, wc = wid & 1;
  const int l15 = lane & 15, lg = lane >> 4;
  f32x4 acc[4][4];
  #pragma unroll
  for (int i = 0; i < 4; ++i)
    #pragma unroll
    for (int j = 0; j < 4; ++j) { f32x4 z = {0.f,0.f,0.f,0.f}; acc[i][j] = z; }
  const u16* Abase = A + (size_t)(bm * 128) * K;
  const int ar0 = tid >> 2;
  const int ac0 = (tid & 3) * 8;
  const int brow = tid >> 3;
  const int bc0 = (tid & 7) * 16;
  for (int kt = 0; kt < K; kt += 32) {
    *(u16x8*)(Al + ar0 * 32 + ac0) =
        *(const u16x8*)(Abase + (size_t)ar0 * K + kt + ac0);
    *(u16x8*)(Al + (ar0 + 64) * 32 + ac0) =
        *(const u16x8*)(Abase + (size_t)(ar0 + 64) * K + kt + ac0);
    {
      const float* bsrc = B0 + (size_t)(kt + brow) * N + bn * 128 + bc0;
      alignas(16) u16 tmp[16];
      const int colbase = bn * 128 + bc0;
      #pragma unroll
      for (int q = 0; q < 16; ++q)
        tmp[q] = f2bf((colbase + q < N) ? bsrc[q] : 0.0f);
      *(u16x8*)(Bl + brow * 128 + bc0) = *(const u16x8*)tmp;
      *(u16x8*)(Bl + brow * 128 + bc0 + 8) = *(const u16x8*)(tmp + 8);
    }
    __syncthreads();
    bf16x8 af[4];
    #pragma unroll
    for (int mi = 0; mi < 4; ++mi)
      af[mi] = *(const bf16x8*)(Al + (wr * 64 + mi * 16 + l15) * 32 + lg * 8);
    #pragma unroll
    for (int ni = 0; ni < 4; ++ni) {
      u16x8 tv;
      #pragma unroll
      for (int i = 0; i < 8; ++i)
        tv[i] = Bl[(lg * 8 + i) * 128 + wc * 64 + ni * 16 + l15];
      const bf16x8 bfr = __builtin_bit_cast(bf16x8, tv);
      #pragma unroll
      for (int mi = 0; mi < 4; ++mi)
        acc[mi][ni] = __builtin_amdgcn_mfma_f32_16x16x32_bf16(af[mi], bfr, acc[mi][ni], 0, 0, 0);
    }
    __syncthreads();
  }
  #pragma unroll
  for (int mi = 0; mi < 4; ++mi) {
    const int grow = bm * 128 + wr * 64 + mi * 16 + lg * 4;
    #pragma unroll
    for (int ni = 0; ni < 4; ++ni) {
      const int gcol = bn * 128 + wc * 64 + ni * 16 + l15;
      #pragma unroll
      for (int r = 0; r < 4; ++r)
        if (gcol < N) of[(size_t)(grow + r) * N + gcol] = acc[mi][ni][r] + bias[gcol];
    }
  }
}

// ------ causal flash attention: 4 q-tiles (256 rows) per block, 8 waves ------
// grid (T/256, B*H), 512 thr. Wave w owns TWO 16-row q-groups g=0,1 at
// qwr_g = bx*256 + g*128 + w*16 (all state duplicated per group). K/V staged
// ONCE per kv-tile for all 256 q-rows. Causal skip wave-uniform per group.
__global__ __launch_bounds__(512, 2) void k_attn(
    const u16* __restrict__ qg, const u16* __restrict__ kg,
    const u16* __restrict__ vg, u16* __restrict__ og) {
  __shared__ u16 Kl[64 * 64];
  __shared__ u16 Vt[64 * 64];
  __shared__ u16 Pl[8][2][16 * 64];   // 32 KB
  const int tid = threadIdx.x;
  const int lane = tid & 63;
  const int w = tid >> 6;            // 0..7
  const int bx = blockIdx.x;         // 0..T/256-1
  const int bh = blockIdx.y;
  const int b = bh >> 4, h = bh & 15;
  const int l15 = lane & 15, lg = lane >> 4;
  char* KlB = (char*)Kl;
  char* VtB = (char*)Vt;

  int qwr[2], diagkt[2];
  size_t qrow0[2];
  bf16x8 aq[2][2];
  #pragma unroll
  for (int g = 0; g < 2; ++g) {
    qwr[g] = bx * 256 + g * 128 + w * 16;
    diagkt[g] = qwr[g] >> 6;
    qrow0[g] = (size_t)b * cT + qwr[g];
    #pragma unroll
    for (int c = 0; c < 2; ++c)
      aq[g][c] = *(const bf16x8*)(qg + (qrow0[g] + l15) * cE + h * 64 + c * 32 + lg * 8);
  }

  f32x4 acco[2][4];
  float mrun[2][4], lrun[2][4];
  #pragma unroll
  for (int g = 0; g < 2; ++g) {
    #pragma unroll
    for (int j = 0; j < 4; ++j) { f32x4 z = {0.f,0.f,0.f,0.f}; acco[g][j] = z; }
    #pragma unroll
    for (int r = 0; r < 4; ++r) { mrun[g][r] = -1e30f; lrun[g][r] = 0.f; }
  }

  const int ktmax = 4 * bx + 3;
  for (int kt = 0; kt <= ktmax; ++kt) {
    const size_t krow0 = (size_t)b * cT + kt * 64;
    {
      const int rr = tid >> 3, c8 = (tid & 7) * 8;   // 512 thr cover 64x64
      *(u16x8*)(KlB + rr * 128 + swzoff(rr, c8 >> 3)) =
          *(const u16x8*)(kg + (krow0 + rr) * cE + h * 64 + c8);
      const u16x8 vv = *(const u16x8*)(vg + (krow0 + rr) * cE + h * 64 + c8);
      #pragma unroll
      for (int i = 0; i < 8; ++i)
        *(u16*)(VtB + (c8 + i) * 128 + swzoff(c8 + i, rr >> 3) + (rr & 7) * 2) = vv[i];
    }
    __syncthreads();

    #pragma unroll
    for (int g = 0; g < 2; ++g) {
      if (kt <= diagkt[g]) {                 // wave-uniform causal skip
        char* PlB = (char*)(Pl[w][g]);
        f32x4 s[4];
        #pragma unroll
        for (int j = 0; j < 4; ++j) { f32x4 z = {0.f,0.f,0.f,0.f}; s[j] = z; }
        #pragma unroll
        for (int c = 0; c < 2; ++c) {
          #pragma unroll
          for (int j = 0; j < 4; ++j) {
            const int n = j * 16 + l15;
            const bf16x8 kb2 = *(const bf16x8*)(KlB + n * 128 + swzoff(n, c * 4 + lg));
            s[j] = __builtin_amdgcn_mfma_f32_16x16x32_bf16(aq[g][c], kb2, s[j], 0, 0, 0);
          }
        }

        float sv[4][4];
        const bool diag = (kt == diagkt[g]);
        #pragma unroll
        for (int j = 0; j < 4; ++j)
          #pragma unroll
          for (int r = 0; r < 4; ++r) {
            float xs = s[j][r] * 0.125f;
            if (diag && (kt * 64 + j * 16 + l15) > (qwr[g] + lg * 4 + r)) xs = -1e30f;
            sv[j][r] = xs;
          }

        float corr[4];
        #pragma unroll
        for (int r = 0; r < 4; ++r) {
          float mx = fmaxf(fmaxf(sv[0][r], sv[1][r]), fmaxf(sv[2][r], sv[3][r]));
          #pragma unroll
          for (int off = 1; off < 16; off <<= 1) mx = fmaxf(mx, __shfl_xor(mx, off));
          const float mnew = fmaxf(mrun[g][r], mx);
          corr[r] = __expf(mrun[g][r] - mnew);
          float rs = 0.f;
          #pragma unroll
          for (int j = 0; j < 4; ++j) {
            const float p = __expf(sv[j][r] - mnew);
            sv[j][r] = p;
            rs += p;
          }
          #pragma unroll
          for (int off = 1; off < 16; off <<= 1) rs += __shfl_xor(rs, off);
          lrun[g][r] = lrun[g][r] * corr[r] + rs;
          mrun[g][r] = mnew;
        }

        #pragma unroll
        for (int j = 0; j < 4; ++j)
          #pragma unroll
          for (int r = 0; r < 4; ++r) {
            const int qr = lg * 4 + r, kc = j * 16 + l15;
            *(u16*)(PlB + qr * 128 + swzoff(qr, kc >> 3) + (kc & 7) * 2) = f2bf(sv[j][r]);
            acco[g][j][r] *= corr[r];
          }

        #pragma unroll
        for (int c = 0; c < 2; ++c) {
          const bf16x8 pa = *(const bf16x8*)(PlB + l15 * 128 + swzoff(l15, c * 4 + lg));
          #pragma unroll
          for (int j = 0; j < 4; ++j) {
            const int n = j * 16 + l15;
            const bf16x8 vb2 = *(const bf16x8*)(VtB + n * 128 + swzoff(n, c * 4 + lg));
            acco[g][j] = __builtin_amdgcn_mfma_f32_16x16x32_bf16(pa, vb2, acco[g][j], 0, 0, 0);
          }
        }
      }
    }
    __syncthreads();
  }

  #pragma unroll
  for (int g = 0; g < 2; ++g)
    #pragma unroll
    for (int j = 0; j < 4; ++j)
      #pragma unroll
      for (int r = 0; r < 4; ++r)
        og[(qrow0[g] + lg * 4 + r) * cE + h * 64 + j * 16 + l15] =
            f2bf(acco[g][j][r] / lrun[g][r]);
}

// ---------------- NLL from per-tile partials ----------------
__global__ __launch_bounds__(256) void k_nll2(const float* __restrict__ pm,
    const float* __restrict__ ps, const float* __restrict__ logits,
    const int* __restrict__ tgt, float* __restrict__ nll, int NT) {
  const int row = blockIdx.x * 4 + (threadIdx.x >> 6);
  const int lane = threadIdx.x & 63;
  float m = -1e30f, s = 0.f;
  for (int i = lane; i < NT; i += 64) {
    const float m2 = pm[(size_t)row * NT + i];
    const float s2 = ps[(size_t)row * NT + i];
    const float M = fmaxf(m, m2);
    s = s * __expf(m - M) + s2 * __expf(m2 - M);
    m = M;
  }
  #pragma unroll
  for (int off = 1; off < 64; off <<= 1) {
    const float m2 = __shfl_xor(m, off);
    const float s2 = __shfl_xor(s, off);
    const float M = fmaxf(m, m2);
    s = s * __expf(m - M) + s2 * __expf(m2 - M);
    m = M;
  }
  if (lane == 0)
    nll[row] = logf(s) + m - logits[(size_t)row * cV + tgt[row]];
}

// ---------------- per-row NLL over V (fallback) ----------------
__global__ __launch_bounds__(256) void k_nll(const float* __restrict__ logits,
    const int* __restrict__ tgt, float* __restrict__ nll) {
  const int row = blockIdx.x;
  const float* lp = logits + (size_t)row * cV;
  const int t = threadIdx.x;
  __shared__ float red[8];
  const int wid = t >> 6, lane = t & 63;
  float mx = -1e30f;
  for (int i = t; i < cV; i += 256) mx = fmaxf(mx, lp[i]);
  #pragma unroll
  for (int off = 32; off; off >>= 1) mx = fmaxf(mx, __shfl_xor(mx, off));
  if (lane == 0) red[wid] = mx;
  __syncthreads();
  mx = fmaxf(fmaxf(red[0], red[1]), fmaxf(red[2], red[3]));
  float s = 0.f;
  for (int i = t; i < cV; i += 256) s += __expf(lp[i] - mx);
  #pragma unroll
  for (int off = 32; off; off >>= 1) s += __shfl_xor(s, off);
  if (lane == 0) red[4 + wid] = s;
  __syncthreads();
  if (t == 0) {
    s = red[4] + red[5] + red[6] + red[7];
    nll[row] = logf(s) + mx - lp[tgt[row]];
  }
}

__global__ __launch_bounds__(256) void k_loss(const float* __restrict__ nll,
    float* __restrict__ out) {
  const int t = threadIdx.x;
  float s = 0.f;
  for (int i = t; i < cBT; i += 256) s += nll[i];
  #pragma unroll
  for (int off = 32; off; off >>= 1) s += __shfl_xor(s, off);
  __shared__ float red[4];
  if ((t & 63) == 0) red[t >> 6] = s;
  __syncthreads();
  if (t == 0) out[0] = (red[0] + red[1] + red[2] + red[3]) * (1.0f / cBT);
}

extern "C" void kernel_launch(void* const* d_in, const int* in_sizes, int n_in,
                              void* d_out, int out_size, void* d_ws, size_t ws_size,
                              hipStream_t stream) {
  const int*   idx  = (const int*)d_in[0];
  const int*   tgt  = (const int*)d_in[1];
  const float* tok  = (const float*)d_in[2];
  const float* pos  = (const float*)d_in[3];
  const float* Wq   = (const float*)d_in[4];
  const float* Wk   = (const float*)d_in[5];
  const float* Wv   = (const float*)d_in[6];
  const float* Wo   = (const float*)d_in[7];
  const float* bo   = (const float*)d_in[8];
  const float* ln1g = (const float*)d_in[9];
  const float* ln1b = (const float*)d_in[10];
  const float* ln2g = (const float*)d_in[11];
  const float* ln2b = (const float*)d_in[12];
  const float* W1   = (const float*)d_in[13];
  const float* b1   = (const float*)d_in[14];
  const float* W2   = (const float*)d_in[15];
  const float* b2   = (const float*)d_in[16];
  const float* lnfg = (const float*)d_in[17];
  const float* lnfb = (const float*)d_in[18];
  const float* Wh   = (const float*)d_in[19];
  const float* bh   = (const float*)d_in[20];

  // --- d_out scratch plan (all dead before head GEMM overwrites d_out) ---
  char* ob = (char*)d_out;
  u16* x      = (u16*)ob;                            // [BT,E] bf16, 8 MB
  u16* hb     = (u16*)(ob + (16u << 20));
  u16* qb     = (u16*)(ob + (24u << 20));            // q/k/v contiguous slabs
  u16* kb     = (u16*)(ob + (32u << 20));
  u16* vb     = (u16*)(ob + (40u << 20));
  u16* abuf   = (u16*)(ob + (48u << 20));
  u16* fbuf   = (u16*)(ob + (56u << 20));            // [BT,FF] bf16 -> ends 88M
  u16* W3T    = (u16*)(ob + (128u << 20));           // 12 x [3][E][E] (72MB) -> 200M
  u16* WoT    = (u16*)(ob + (200u << 20));           // 12 x [E][E]   (24MB) -> 224M
  u16* W1T    = (u16*)(ob + (224u << 20));           // 12 x [FF][E]  (96MB) -> 320M
  u16* W2T    = (u16*)(ob + (320u << 20));           // 12 x [E][FF]  (96MB) -> 416M
  // --- d_ws layout ---
  u16* hf     = (u16*)d_ws;                          // 8.39 MB
  float* nll  = (float*)((char*)d_ws + 8388608);
  u16* WheadT = (u16*)((char*)d_ws + 8404992);       // [cVp][E] bf16 (103.3 MB)
  const size_t whead_end = 8404992u + (size_t)cVp * cE * 2u;
  float* pmax = (float*)((char*)d_ws + whead_end);
  float* psum = (float*)((char*)d_ws + whead_end + (size_t)cBT * cNT * 4);
  const size_t ws_need = whead_end + 2u * (size_t)cBT * cNT * 4;
  const bool fast_head = ws_size >= ws_need;

  float* logits = (float*)d_out;
  float* loss = logits + (size_t)cBT * cV;

  const dim3 blk(256);
  const size_t e2 = (size_t)cE * cE, ef = (size_t)cE * cFF;

  // weight conversion (every call)
  k_cvt_t<<<dim3(16, 32, cL), blk, 0, stream>>>(Wq, W3T,          cE, cE, e2, 3 * e2);
  k_cvt_t<<<dim3(16, 32, cL), blk, 0, stream>>>(Wk, W3T + e2,     cE, cE, e2, 3 * e2);
  k_cvt_t<<<dim3(16, 32, cL), blk, 0, stream>>>(Wv, W3T + 2 * e2, cE, cE, e2, 3 * e2);
  k_cvt_t<<<dim3(16, 32, cL), blk, 0, stream>>>(Wo, WoT, cE, cE, e2, e2);
  k_cvt_t<<<dim3(64, 32, cL), blk, 0, stream>>>(W1, W1T, cE, cFF, ef, ef);
  k_cvt_t<<<dim3(16, 128, cL), blk, 0, stream>>>(W2, W2T, cFF, cE, ef, ef);
  if (fast_head)
    k_cvt_t<<<dim3(cVp / 64, 32, 1), blk, 0, stream>>>(Wh, WheadT, cE, cV, 0, 0);

  k_embed<<<dim3(cBT), blk, 0, stream>>>(idx, tok, pos, x);
  for (int l = 0; l < cL; ++l) {
    k_ln<<<dim3(cBT / 4), blk, 0, stream>>>(x, ln1g + l * cE, ln1b + l * cE, hb);
    k_gemm2<0><<<dim3(32 * 12), dim3(512), 0, stream>>>(hb, W3T + l * 3 * e2,
        nullptr, qb, nullptr, cE, 3072, 0, 32, nullptr, nullptr);
    k_attn<<<dim3(4, 64), dim3(512), 0, stream>>>(qb, kb, vb, abuf);
    k_gemm_s<<<dim3(512), blk, 0, stream>>>(abuf, WoT + l * e2, bo + l * cE, x, cE, cE, 64);
    k_ln<<<dim3(cBT / 4), blk, 0, stream>>>(x, ln2g + l * cE, ln2b + l * cE, hb);
    k_gemm2<2><<<dim3(32 * 16), dim3(512), 0, stream>>>(hb, W1T + l * ef,
        b1 + l * cFF, fbuf, nullptr, cE, cFF, 0, 32, nullptr, nullptr);
    k_gemm_s<<<dim3(512), blk, 0, stream>>>(fbuf, W2T + l * ef, b2 + l * cE, x, cFF, cE, 64);
  }
  k_ln<<<dim3(cBT / 4), blk, 0, stream>>>(x, lnfg, lnfb, hf);
  if (fast_head) {
    k_gemm2<3><<<dim3(32 * cNT), dim3(512), 0, stream>>>(hf, WheadT, bh,
        nullptr, logits, cE, cV, cNT, 32, pmax, psum);
    k_nll2<<<dim3(cBT / 4), blk, 0, stream>>>(pmax, psum, logits, tgt, nll, cNT);
  } else {
    k_gemm_legacy3<<<dim3(393, 32), blk, 0, stream>>>(hf, Wh, bh, logits, cBT, cV, cE);
    k_nll<<<dim3(cBT), blk, 0, stream>>>(logits, tgt, nll);
  }
  k_loss<<<dim3(1), blk, 0, stream>>>(nll, loss);
}